// Round 7
// baseline (918.928 us; speedup 1.0000x reference)
//
#include <hip/hip_runtime.h>
#include <stdint.h>

#define N_NODES 50000
#define N_EDGES 800000
#define FEAT    128
#define NGRAPH  64

typedef __attribute__((ext_vector_type(8))) short short8;
typedef __attribute__((ext_vector_type(8))) unsigned short ushortv8;
typedef __attribute__((ext_vector_type(4))) float floatx4;

static __device__ __forceinline__ ushort f2bf(float f) {
  uint32_t x = __float_as_uint(f);
  x += 0x7FFF + ((x >> 16) & 1);   // RNE
  return (ushort)(x >> 16);
}
static __device__ __forceinline__ float bfLo(uint32_t u) {
  return __uint_as_float(u << 16);
}
static __device__ __forceinline__ float bfHi(uint32_t u) {
  return __uint_as_float(u & 0xFFFF0000u);
}

// ---------------- fp32 -> bf16 row-major ---------------------------------
__global__ __launch_bounds__(256) void cvt_bf16(const float* __restrict__ in,
                                                ushort* __restrict__ out, int n4) {
  int i = blockIdx.x * 256 + threadIdx.x;
  if (i >= n4) return;
  float4 v = ((const float4*)in)[i];
  ushort4 u;
  u.x = f2bf(v.x); u.y = f2bf(v.y); u.z = f2bf(v.z); u.w = f2bf(v.w);
  ((ushort4*)out)[i] = u;
}

// ---------------- degree count -------------------------------------------
__global__ __launch_bounds__(256) void count_deg(const int* __restrict__ dst,
                                                 int* __restrict__ cnt) {
  int e = blockIdx.x * 256 + threadIdx.x;
  if (e < N_EDGES) atomicAdd(&cnt[dst[e]], 1);
}

__global__ __launch_bounds__(256) void compute_dinv(const int* __restrict__ cnt,
                                                    float* __restrict__ dinv) {
  int i = blockIdx.x * 256 + threadIdx.x;
  if (i < N_NODES) dinv[i] = rsqrtf((float)cnt[i] + 1.0f);
}

// ---------------- exclusive scan (3 kernels) -----------------------------
__global__ __launch_bounds__(256) void scan1(const int* __restrict__ cnt,
                                             int* __restrict__ ptr,
                                             int* __restrict__ bsums) {
  __shared__ int tmp[256];
  int i = blockIdx.x * 256 + threadIdx.x;
  int v = (i < N_NODES) ? cnt[i] : 0;
  tmp[threadIdx.x] = v;
  __syncthreads();
  for (int off = 1; off < 256; off <<= 1) {
    int t = (threadIdx.x >= off) ? tmp[threadIdx.x - off] : 0;
    __syncthreads();
    tmp[threadIdx.x] += t;
    __syncthreads();
  }
  if (i < N_NODES) ptr[i] = tmp[threadIdx.x] - v;           // exclusive
  if (threadIdx.x == 255) bsums[blockIdx.x] = tmp[255];
}

__global__ __launch_bounds__(256) void scan2(int* __restrict__ bsums, int nb) {
  __shared__ int tmp[256];
  int v = (threadIdx.x < nb) ? bsums[threadIdx.x] : 0;
  tmp[threadIdx.x] = v;
  __syncthreads();
  for (int off = 1; off < 256; off <<= 1) {
    int t = (threadIdx.x >= off) ? tmp[threadIdx.x - off] : 0;
    __syncthreads();
    tmp[threadIdx.x] += t;
    __syncthreads();
  }
  if (threadIdx.x < nb) bsums[threadIdx.x] = tmp[threadIdx.x] - v;  // exclusive
}

__global__ __launch_bounds__(256) void scan3(int* __restrict__ ptr,
                                             int* __restrict__ cursor,
                                             const int* __restrict__ bsums) {
  int i = blockIdx.x * 256 + threadIdx.x;
  if (i < N_NODES) {
    int p = ptr[i] + bsums[blockIdx.x];
    ptr[i] = p;
    cursor[i] = p;
  }
}

// ---------------- CSR fill (src + fused norm) ----------------------------
__global__ __launch_bounds__(256) void fill_csr(const int* __restrict__ src,
                                                const int* __restrict__ dst,
                                                const float* __restrict__ dinv,
                                                int* __restrict__ cursor,
                                                int2* __restrict__ edges) {
  int e = blockIdx.x * 256 + threadIdx.x;
  if (e >= N_EDGES) return;
  int s = src[e], d = dst[e];
  int pos = atomicAdd(&cursor[d], 1);
  float nrm = dinv[s] * dinv[d];
  edges[pos] = make_int2(s, __float_as_int(nrm));
}

// ---------------- GEMM [M,128] x [128,128] via MFMA bf16, bf16 out -------
__global__ __launch_bounds__(256) void gemm128(const ushort* __restrict__ X,
                                               const ushort* __restrict__ W,
                                               ushort* __restrict__ XW,
                                               int nTilesM) {
  int wave = (blockIdx.x * 256 + threadIdx.x) >> 6;
  int lane = threadIdx.x & 63;
  int mt = wave >> 3;  // 8 n-tiles per m-tile
  int nt = wave & 7;
  if (mt >= nTilesM) return;
  int m0 = mt * 16, n0 = nt * 16;
  int r = lane & 15, quad = lane >> 4;
  floatx4 acc = {0.f, 0.f, 0.f, 0.f};
  const ushort* xrow = X + (size_t)(m0 + r) * FEAT;
#pragma unroll
  for (int kb = 0; kb < 4; ++kb) {
    int k0 = kb * 32 + quad * 8;
    short8 a = *(const short8*)(xrow + k0);
    short8 b;
#pragma unroll
    for (int j = 0; j < 8; ++j) b[j] = (short)W[(size_t)(k0 + j) * FEAT + n0 + r];
    acc = __builtin_amdgcn_mfma_f32_16x16x32_bf16(a, b, acc, 0, 0, 0);
  }
#pragma unroll
  for (int reg = 0; reg < 4; ++reg) {
    int row = quad * 4 + reg;
    XW[(size_t)(m0 + row) * FEAT + n0 + r] = f2bf(acc[reg]);
  }
}

// ---------------- aggregation: wave/node, 4 edges per gather inst --------
// msg: bf16 [N][128] (256B rows). subgroup g=lane>>4 handles edge i+g;
// lane t=lane&15 loads 16B (features 8t..8t+7) of that edge's row.
// One dwordx4 gather instruction covers 4 edges. Unroll 2 -> 8 edges/iter.
// mode 0: h = relu(agg + b) -> bf16 Hout;  mode 1: atomicAdd into f_sum.
__global__ __launch_bounds__(256) void agg_kernel(const ushort* __restrict__ msg,
                                                  const float* __restrict__ dinv,
                                                  const int* __restrict__ ptr,
                                                  const int* __restrict__ cnt,
                                                  const int2* __restrict__ edges,
                                                  const float* __restrict__ bias,
                                                  ushort* __restrict__ Hout,
                                                  float* __restrict__ f_sum,
                                                  const int* __restrict__ batch,
                                                  int mode) {
  int wave = (blockIdx.x * 256 + threadIdx.x) >> 6;
  int lane = threadIdx.x & 63;
  if (wave >= N_NODES) return;
  int v = wave;
  int g = lane >> 4;        // edge subgroup 0..3
  int t = lane & 15;        // 16B chunk within row
  float a0 = 0.f, a1 = 0.f, a2 = 0.f, a3 = 0.f;
  float a4 = 0.f, a5 = 0.f, a6 = 0.f, a7 = 0.f;
  // self-loop handled by subgroup 0
  if (g == 0) {
    float di = dinv[v];
    float sn = di * di;
    uint4 u = *(const uint4*)(msg + (size_t)v * FEAT + t * 8);
    a0 = sn * bfLo(u.x); a1 = sn * bfHi(u.x);
    a2 = sn * bfLo(u.y); a3 = sn * bfHi(u.y);
    a4 = sn * bfLo(u.z); a5 = sn * bfHi(u.z);
    a6 = sn * bfLo(u.w); a7 = sn * bfHi(u.w);
  }
  int start = ptr[v];
  int n = cnt[v];
  int i = 0;
  // main loop: 8 edges per iteration (2 gather insts in flight)
  for (; i + 8 <= n; i += 8) {
    int2 ea = edges[start + i + g];
    int2 eb = edges[start + i + 4 + g];
    uint4 ua = *(const uint4*)(msg + (size_t)ea.x * FEAT + t * 8);
    uint4 ub = *(const uint4*)(msg + (size_t)eb.x * FEAT + t * 8);
    float na = __int_as_float(ea.y);
    float nb = __int_as_float(eb.y);
    a0 = fmaf(na, bfLo(ua.x), a0); a1 = fmaf(na, bfHi(ua.x), a1);
    a2 = fmaf(na, bfLo(ua.y), a2); a3 = fmaf(na, bfHi(ua.y), a3);
    a4 = fmaf(na, bfLo(ua.z), a4); a5 = fmaf(na, bfHi(ua.z), a5);
    a6 = fmaf(na, bfLo(ua.w), a6); a7 = fmaf(na, bfHi(ua.w), a7);
    a0 = fmaf(nb, bfLo(ub.x), a0); a1 = fmaf(nb, bfHi(ub.x), a1);
    a2 = fmaf(nb, bfLo(ub.y), a2); a3 = fmaf(nb, bfHi(ub.y), a3);
    a4 = fmaf(nb, bfLo(ub.z), a4); a5 = fmaf(nb, bfHi(ub.z), a5);
    a6 = fmaf(nb, bfLo(ub.w), a6); a7 = fmaf(nb, bfHi(ub.w), a7);
  }
  // remainder: 4-edge steps with norm=0 masking (at most 2 steps)
  for (; i < n; i += 4) {
    int idx = i + g;
    int2 e = edges[start + (idx < n ? idx : n - 1)];
    float nrm = (idx < n) ? __int_as_float(e.y) : 0.f;
    uint4 u = *(const uint4*)(msg + (size_t)e.x * FEAT + t * 8);
    a0 = fmaf(nrm, bfLo(u.x), a0); a1 = fmaf(nrm, bfHi(u.x), a1);
    a2 = fmaf(nrm, bfLo(u.y), a2); a3 = fmaf(nrm, bfHi(u.y), a3);
    a4 = fmaf(nrm, bfLo(u.z), a4); a5 = fmaf(nrm, bfHi(u.z), a5);
    a6 = fmaf(nrm, bfLo(u.w), a6); a7 = fmaf(nrm, bfHi(u.w), a7);
  }
  // reduce across the 4 subgroups -> lanes 0..15
  a0 += __shfl_down(a0, 32, 64); a1 += __shfl_down(a1, 32, 64);
  a2 += __shfl_down(a2, 32, 64); a3 += __shfl_down(a3, 32, 64);
  a4 += __shfl_down(a4, 32, 64); a5 += __shfl_down(a5, 32, 64);
  a6 += __shfl_down(a6, 32, 64); a7 += __shfl_down(a7, 32, 64);
  a0 += __shfl_down(a0, 16, 64); a1 += __shfl_down(a1, 16, 64);
  a2 += __shfl_down(a2, 16, 64); a3 += __shfl_down(a3, 16, 64);
  a4 += __shfl_down(a4, 16, 64); a5 += __shfl_down(a5, 16, 64);
  a6 += __shfl_down(a6, 16, 64); a7 += __shfl_down(a7, 16, 64);
  if (lane < 16) {
    float4 b0 = *(const float4*)(bias + t * 8);
    float4 b1 = *(const float4*)(bias + t * 8 + 4);
    float v0 = a0 + b0.x, v1 = a1 + b0.y, v2 = a2 + b0.z, v3 = a3 + b0.w;
    float v4 = a4 + b1.x, v5 = a5 + b1.y, v6 = a6 + b1.z, v7 = a7 + b1.w;
    if (mode == 0) {
      v0 = fmaxf(v0, 0.f); v1 = fmaxf(v1, 0.f);
      v2 = fmaxf(v2, 0.f); v3 = fmaxf(v3, 0.f);
      v4 = fmaxf(v4, 0.f); v5 = fmaxf(v5, 0.f);
      v6 = fmaxf(v6, 0.f); v7 = fmaxf(v7, 0.f);
      ushortv8 h;
      h[0] = f2bf(v0); h[1] = f2bf(v1); h[2] = f2bf(v2); h[3] = f2bf(v3);
      h[4] = f2bf(v4); h[5] = f2bf(v5); h[6] = f2bf(v6); h[7] = f2bf(v7);
      *(ushortv8*)(Hout + (size_t)v * FEAT + t * 8) = h;
    } else {
      int gr = batch[v];
      float* fs = f_sum + gr * FEAT + t * 8;
      atomicAdd(fs + 0, v0); atomicAdd(fs + 1, v1);
      atomicAdd(fs + 2, v2); atomicAdd(fs + 3, v3);
      atomicAdd(fs + 4, v4); atomicAdd(fs + 5, v5);
      atomicAdd(fs + 6, v6); atomicAdd(fs + 7, v7);
    }
  }
}

// ---------------- per-graph node counts (LDS binned) ---------------------
__global__ __launch_bounds__(256) void count_graphs(const int* __restrict__ batch,
                                                    float* __restrict__ cnt_g) {
  __shared__ int bins[NGRAPH];
  if (threadIdx.x < NGRAPH) bins[threadIdx.x] = 0;
  __syncthreads();
  int i = blockIdx.x * 256 + threadIdx.x;
  if (i < N_NODES) atomicAdd(&bins[batch[i]], 1);
  __syncthreads();
  if (threadIdx.x < NGRAPH && bins[threadIdx.x] > 0)
    atomicAdd(&cnt_g[threadIdx.x], (float)bins[threadIdx.x]);
}

// ---------------- finalize f = sums / cnt (fp32, output 0) ---------------
__global__ __launch_bounds__(256) void finalize_f(const float* __restrict__ f_sum,
                                                  const float* __restrict__ cnt_g,
                                                  float* __restrict__ out_f) {
  int i = blockIdx.x * 256 + threadIdx.x;
  if (i < NGRAPH * FEAT) {
    float c = fmaxf(cnt_g[i >> 7], 1.0f);
    out_f[i] = f_sum[i] / c;
  }
}

// ---------------- FC head: split-K atomic GEMM ---------------------------
__global__ __launch_bounds__(256) void fc_init(const float* __restrict__ b,
                                               float* __restrict__ out, int C) {
  int i = blockIdx.x * 256 + threadIdx.x;
  if (i < NGRAPH * C) out[i] = b[i % C];
}

__global__ __launch_bounds__(256) void fc_accum(const float* __restrict__ in,
                                                const float* __restrict__ w,
                                                float* __restrict__ out,
                                                int K, int C, int relu_in,
                                                int cstrips, int kchunks) {
  int wave = (blockIdx.x * 256 + threadIdx.x) >> 6;
  int lane = threadIdx.x & 63;
  int perrow = cstrips * kchunks;
  int r = wave / perrow;
  if (r >= NGRAPH) return;
  int rem = wave - r * perrow;
  int cs = rem / kchunks;
  int kc = rem - cs * kchunks;
  int c = cs * 64 + lane;
  if (c >= C) return;
  const float* inr = in + (size_t)r * K + kc * 64;
  const float* wp = w + (size_t)(kc * 64) * C + c;
  float a0 = 0.f, a1 = 0.f, a2 = 0.f, a3 = 0.f;
#pragma unroll 4
  for (int k = 0; k < 64; k += 4) {
    float i0 = inr[k], i1 = inr[k + 1], i2 = inr[k + 2], i3 = inr[k + 3];
    if (relu_in) {
      i0 = fmaxf(i0, 0.f); i1 = fmaxf(i1, 0.f);
      i2 = fmaxf(i2, 0.f); i3 = fmaxf(i3, 0.f);
    }
    a0 = fmaf(i0, wp[(size_t)k * C], a0);
    a1 = fmaf(i1, wp[(size_t)(k + 1) * C], a1);
    a2 = fmaf(i2, wp[(size_t)(k + 2) * C], a2);
    a3 = fmaf(i3, wp[(size_t)(k + 3) * C], a3);
  }
  atomicAdd(&out[(size_t)r * C + c], (a0 + a1) + (a2 + a3));
}

static inline void fc_run(const float* in, const float* w, const float* b,
                          float* out, int K, int C, int relu_in,
                          hipStream_t stream) {
  int cstrips = (C + 63) / 64;
  int kchunks = K / 64;
  fc_init<<<(NGRAPH * C + 255) / 256, 256, 0, stream>>>(b, out, C);
  int waves = NGRAPH * cstrips * kchunks;
  fc_accum<<<(waves * 64 + 255) / 256, 256, 0, stream>>>(in, w, out, K, C,
                                                         relu_in, cstrips, kchunks);
}

// =========================================================================
extern "C" void kernel_launch(void* const* d_in, const int* in_sizes, int n_in,
                              void* d_out, int out_size, void* d_ws, size_t ws_size,
                              hipStream_t stream) {
  const float* x         = (const float*)d_in[0];
  const int*   ei        = (const int*)d_in[1];     // [2][E]: row0 src, row1 dst
  const int*   batch     = (const int*)d_in[2];
  const float* conv_w[3] = {(const float*)d_in[3], (const float*)d_in[5], (const float*)d_in[7]};
  const float* conv_b[3] = {(const float*)d_in[4], (const float*)d_in[6], (const float*)d_in[8]};
  const float* fc_w[5]   = {(const float*)d_in[9],  (const float*)d_in[11],
                            (const float*)d_in[13], (const float*)d_in[15],
                            (const float*)d_in[17]};
  const float* fc_b[5]   = {(const float*)d_in[10], (const float*)d_in[12],
                            (const float*)d_in[14], (const float*)d_in[16],
                            (const float*)d_in[18]};
  const int* e_src = ei;
  const int* e_dst = ei + N_EDGES;
  float* out_f = (float*)d_out;                  // [64][128] fp32  (output 0)
  float* out_y = (float*)d_out + NGRAPH * FEAT;  // [64][10]  fp32  (output 1)

  char* p = (char*)d_ws;
  auto carve = [&](size_t bytes) {
    char* r = p;
    p += (bytes + 255) & ~(size_t)255;
    return r;
  };
  int*    cnt_i   = (int*)carve(N_NODES * 4);
  float*  dinv    = (float*)carve(N_NODES * 4);
  int*    csr_ptr = (int*)carve(N_NODES * 4);
  int*    cursor  = (int*)carve(N_NODES * 4);
  int*    bsums   = (int*)carve(256 * 4);
  int2*   edges   = (int2*)carve((size_t)N_EDGES * 8);
  ushort* xb      = (ushort*)carve((size_t)N_NODES * FEAT * 2);   // bf16 x
  ushort* wb      = (ushort*)carve((size_t)3 * FEAT * FEAT * 2);  // bf16 conv weights
  ushort* msl     = (ushort*)carve((size_t)N_NODES * FEAT * 2);   // bf16 messages XW
  ushort* hbuf    = (ushort*)carve((size_t)N_NODES * FEAT * 2);   // bf16 h
  float*  f_sum   = (float*)carve(NGRAPH * FEAT * 4);
  float*  cnt_g   = (float*)carve(NGRAPH * 4);
  float*  act1    = (float*)carve(NGRAPH * 1024 * 4);
  float*  act2    = (float*)carve(NGRAPH * 512 * 4);
  float*  act3    = (float*)carve(NGRAPH * 256 * 4);
  float*  act4    = (float*)carve(NGRAPH * 128 * 4);

  const int BLK_E = (N_EDGES + 255) / 256;
  const int BLK_N = (N_NODES + 255) / 256;

  hipMemsetAsync(cnt_i, 0, N_NODES * 4, stream);
  hipMemsetAsync(f_sum, 0, NGRAPH * FEAT * 4, stream);
  hipMemsetAsync(cnt_g, 0, NGRAPH * 4, stream);

  // ---- fp32 -> bf16 prep (x, conv weights) ----
  cvt_bf16<<<(N_NODES * FEAT / 4 + 255) / 256, 256, 0, stream>>>(x, xb, N_NODES * FEAT / 4);
  cvt_bf16<<<(FEAT * FEAT / 4 + 255) / 256, 256, 0, stream>>>(conv_w[0], wb,                   FEAT * FEAT / 4);
  cvt_bf16<<<(FEAT * FEAT / 4 + 255) / 256, 256, 0, stream>>>(conv_w[1], wb + FEAT * FEAT,     FEAT * FEAT / 4);
  cvt_bf16<<<(FEAT * FEAT / 4 + 255) / 256, 256, 0, stream>>>(conv_w[2], wb + 2 * FEAT * FEAT, FEAT * FEAT / 4);

  // ---- build CSR + norms (reused by all 3 convs) ----
  count_deg<<<BLK_E, 256, 0, stream>>>(e_dst, cnt_i);
  compute_dinv<<<BLK_N, 256, 0, stream>>>(cnt_i, dinv);
  scan1<<<BLK_N, 256, 0, stream>>>(cnt_i, csr_ptr, bsums);
  scan2<<<1, 256, 0, stream>>>(bsums, BLK_N);
  scan3<<<BLK_N, 256, 0, stream>>>(csr_ptr, cursor, bsums);
  fill_csr<<<BLK_E, 256, 0, stream>>>(e_src, e_dst, dinv, cursor, edges);

  const int GEMM_BLKS = (N_NODES / 16) * 8 / 4;
  const int AGG_BLKS  = (N_NODES + 3) / 4;

  // ---- conv1 ----
  gemm128<<<GEMM_BLKS, 256, 0, stream>>>(xb, wb, msl, N_NODES / 16);
  agg_kernel<<<AGG_BLKS, 256, 0, stream>>>(msl, dinv, csr_ptr, cnt_i, edges,
                                           conv_b[0], hbuf, f_sum, batch, 0);
  // ---- conv2 ----
  gemm128<<<GEMM_BLKS, 256, 0, stream>>>(hbuf, wb + FEAT * FEAT, msl, N_NODES / 16);
  agg_kernel<<<AGG_BLKS, 256, 0, stream>>>(msl, dinv, csr_ptr, cnt_i, edges,
                                           conv_b[1], hbuf, f_sum, batch, 0);
  // ---- conv3 + fused mean-pool numerator ----
  gemm128<<<GEMM_BLKS, 256, 0, stream>>>(hbuf, wb + 2 * FEAT * FEAT, msl, N_NODES / 16);
  agg_kernel<<<AGG_BLKS, 256, 0, stream>>>(msl, dinv, csr_ptr, cnt_i, edges,
                                           conv_b[2], hbuf, f_sum, batch, 1);

  // ---- pool ----
  count_graphs<<<BLK_N, 256, 0, stream>>>(batch, cnt_g);
  finalize_f<<<(NGRAPH * FEAT + 255) / 256, 256, 0, stream>>>(f_sum, cnt_g, out_f);

  // ---- FC head: split-K atomic GEMMs, relu fused into next layer's read ----
  fc_run(out_f, fc_w[0], fc_b[0], act1, 128, 1024, 0, stream);
  fc_run(act1,  fc_w[1], fc_b[1], act2, 1024, 512, 1, stream);
  fc_run(act2,  fc_w[2], fc_b[2], act3, 512, 256, 1, stream);
  fc_run(act3,  fc_w[3], fc_b[3], act4, 256, 128, 1, stream);
  fc_run(act4,  fc_w[4], fc_b[4], out_y, 128, 10, 1, stream);
}

// Round 8
// 635.750 us; speedup vs baseline: 1.4454x; 1.4454x over previous
//
#include <hip/hip_runtime.h>
#include <stdint.h>

#define N_NODES 50000
#define N_EDGES 800000
#define FEAT    128
#define NGRAPH  64
#define CHUNK   256      // pool_gemm LDS chunk (nodes)

typedef __attribute__((ext_vector_type(8))) short short8;
typedef __attribute__((ext_vector_type(4))) float floatx4;

static __device__ __forceinline__ ushort f2bf(float f) {
  uint32_t x = __float_as_uint(f);
  x += 0x7FFF + ((x >> 16) & 1);   // RNE
  return (ushort)(x >> 16);
}
static __device__ __forceinline__ float bfLo(uint32_t u) {
  return __uint_as_float(u << 16);
}
static __device__ __forceinline__ float bfHi(uint32_t u) {
  return __uint_as_float(u & 0xFFFF0000u);
}

// ---------------- fp32 -> bf16 row-major ---------------------------------
__global__ __launch_bounds__(256) void cvt_bf16(const float* __restrict__ in,
                                                ushort* __restrict__ out, int n4) {
  int i = blockIdx.x * 256 + threadIdx.x;
  if (i >= n4) return;
  float4 v = ((const float4*)in)[i];
  ushort4 u;
  u.x = f2bf(v.x); u.y = f2bf(v.y); u.z = f2bf(v.z); u.w = f2bf(v.w);
  ((ushort4*)out)[i] = u;
}

// ---------------- degree count -------------------------------------------
__global__ __launch_bounds__(256) void count_deg(const int* __restrict__ dst,
                                                 int* __restrict__ cnt) {
  int e = blockIdx.x * 256 + threadIdx.x;
  if (e < N_EDGES) atomicAdd(&cnt[dst[e]], 1);
}

// dinv + self-loop coef term (plain store into zeroed coefT; edge terms
// are atomicAdd'ed by the later fill_csr dispatch — stream order safe)
__global__ __launch_bounds__(256) void compute_dinv(const int* __restrict__ cnt,
                                                    const int* __restrict__ batch,
                                                    float* __restrict__ dinv,
                                                    float* __restrict__ coefT) {
  int i = blockIdx.x * 256 + threadIdx.x;
  if (i < N_NODES) {
    float di = rsqrtf((float)cnt[i] + 1.0f);
    dinv[i] = di;
    coefT[(size_t)batch[i] * N_NODES + i] = di * di;
  }
}

// ---------------- exclusive scan (3 kernels) -----------------------------
__global__ __launch_bounds__(256) void scan1(const int* __restrict__ cnt,
                                             int* __restrict__ ptr,
                                             int* __restrict__ bsums) {
  __shared__ int tmp[256];
  int i = blockIdx.x * 256 + threadIdx.x;
  int v = (i < N_NODES) ? cnt[i] : 0;
  tmp[threadIdx.x] = v;
  __syncthreads();
  for (int off = 1; off < 256; off <<= 1) {
    int t = (threadIdx.x >= off) ? tmp[threadIdx.x - off] : 0;
    __syncthreads();
    tmp[threadIdx.x] += t;
    __syncthreads();
  }
  if (i < N_NODES) ptr[i] = tmp[threadIdx.x] - v;           // exclusive
  if (threadIdx.x == 255) bsums[blockIdx.x] = tmp[255];
}

__global__ __launch_bounds__(256) void scan2(int* __restrict__ bsums, int nb) {
  __shared__ int tmp[256];
  int v = (threadIdx.x < nb) ? bsums[threadIdx.x] : 0;
  tmp[threadIdx.x] = v;
  __syncthreads();
  for (int off = 1; off < 256; off <<= 1) {
    int t = (threadIdx.x >= off) ? tmp[threadIdx.x - off] : 0;
    __syncthreads();
    tmp[threadIdx.x] += t;
    __syncthreads();
  }
  if (threadIdx.x < nb) bsums[threadIdx.x] = tmp[threadIdx.x] - v;  // exclusive
}

__global__ __launch_bounds__(256) void scan3(int* __restrict__ ptr,
                                             int* __restrict__ cursor,
                                             const int* __restrict__ bsums) {
  int i = blockIdx.x * 256 + threadIdx.x;
  if (i < N_NODES) {
    int p = ptr[i] + bsums[blockIdx.x];
    ptr[i] = p;
    cursor[i] = p;
  }
}

// ---------------- CSR fill (src + fused norm) + coef edge terms ----------
__global__ __launch_bounds__(256) void fill_csr(const int* __restrict__ src,
                                                const int* __restrict__ dst,
                                                const float* __restrict__ dinv,
                                                const int* __restrict__ batch,
                                                int* __restrict__ cursor,
                                                int2* __restrict__ edges,
                                                float* __restrict__ coefT) {
  int e = blockIdx.x * 256 + threadIdx.x;
  if (e >= N_EDGES) return;
  int s = src[e], d = dst[e];
  int pos = atomicAdd(&cursor[d], 1);
  float nrm = dinv[s] * dinv[d];
  edges[pos] = make_int2(s, __float_as_int(nrm));
  atomicAdd(&coefT[(size_t)batch[d] * N_NODES + s], nrm);
}

// ---------------- GEMM [M,128] x [128,128] via MFMA bf16, bf16 out -------
__global__ __launch_bounds__(256) void gemm128(const ushort* __restrict__ X,
                                               const ushort* __restrict__ W,
                                               ushort* __restrict__ XW,
                                               int nTilesM) {
  int wave = (blockIdx.x * 256 + threadIdx.x) >> 6;
  int lane = threadIdx.x & 63;
  int mt = wave >> 3;  // 8 n-tiles per m-tile
  int nt = wave & 7;
  if (mt >= nTilesM) return;
  int m0 = mt * 16, n0 = nt * 16;
  int r = lane & 15, quad = lane >> 4;
  floatx4 acc = {0.f, 0.f, 0.f, 0.f};
  const ushort* xrow = X + (size_t)(m0 + r) * FEAT;
#pragma unroll
  for (int kb = 0; kb < 4; ++kb) {
    int k0 = kb * 32 + quad * 8;
    short8 a = *(const short8*)(xrow + k0);
    short8 b;
#pragma unroll
    for (int j = 0; j < 8; ++j) b[j] = (short)W[(size_t)(k0 + j) * FEAT + n0 + r];
    acc = __builtin_amdgcn_mfma_f32_16x16x32_bf16(a, b, acc, 0, 0, 0);
  }
#pragma unroll
  for (int reg = 0; reg < 4; ++reg) {
    int row = quad * 4 + reg;
    XW[(size_t)(m0 + row) * FEAT + n0 + r] = f2bf(acc[reg]);
  }
}

// ---------------- aggregation (r6 proven): wave/node, 8-edge ILP ---------
// msg bf16 [N][128]; lane covers features {2*lane, 2*lane+1} (one dword).
// h = relu(agg + b) -> bf16 Hout
__global__ __launch_bounds__(256) void agg_kernel(const ushort* __restrict__ msg,
                                                  const float* __restrict__ dinv,
                                                  const int* __restrict__ ptr,
                                                  const int* __restrict__ cnt,
                                                  const int2* __restrict__ edges,
                                                  const float* __restrict__ bias,
                                                  ushort* __restrict__ Hout) {
  int wave = (blockIdx.x * 256 + threadIdx.x) >> 6;
  int lane = threadIdx.x & 63;
  if (wave >= N_NODES) return;
  int v = wave;
  float di = dinv[v];
  const uint32_t* m32 = (const uint32_t*)msg;   // 64 dwords per node row
  uint32_t su = m32[(size_t)v * 64 + lane];
  float sn = di * di;
  float ax0 = bfLo(su) * sn, ay0 = bfHi(su) * sn;
  float ax1 = 0.f, ay1 = 0.f, ax2 = 0.f, ay2 = 0.f, ax3 = 0.f, ay3 = 0.f;
  int start = ptr[v];
  int n = cnt[v];
  int i = 0;
  if ((start & 1) && n > 0) {
    int2 e = edges[start];
    uint32_t u = m32[(size_t)e.x * 64 + lane];
    float nrm = __int_as_float(e.y);
    ax0 = fmaf(nrm, bfLo(u), ax0);
    ay0 = fmaf(nrm, bfHi(u), ay0);
    i = 1;
  }
  for (; i + 8 <= n; i += 8) {
    const int4* ep = (const int4*)(edges + start + i);   // 16B-aligned
    int4 q0 = ep[0], q1 = ep[1], q2 = ep[2], q3 = ep[3];
    uint32_t u0 = m32[(size_t)q0.x * 64 + lane];
    uint32_t u1 = m32[(size_t)q0.z * 64 + lane];
    uint32_t u2 = m32[(size_t)q1.x * 64 + lane];
    uint32_t u3 = m32[(size_t)q1.z * 64 + lane];
    uint32_t u4 = m32[(size_t)q2.x * 64 + lane];
    uint32_t u5 = m32[(size_t)q2.z * 64 + lane];
    uint32_t u6 = m32[(size_t)q3.x * 64 + lane];
    uint32_t u7 = m32[(size_t)q3.z * 64 + lane];
    float n0 = __int_as_float(q0.y), n1 = __int_as_float(q0.w);
    float n2 = __int_as_float(q1.y), n3 = __int_as_float(q1.w);
    float n4 = __int_as_float(q2.y), n5 = __int_as_float(q2.w);
    float n6 = __int_as_float(q3.y), n7 = __int_as_float(q3.w);
    ax0 = fmaf(n0, bfLo(u0), ax0); ay0 = fmaf(n0, bfHi(u0), ay0);
    ax1 = fmaf(n1, bfLo(u1), ax1); ay1 = fmaf(n1, bfHi(u1), ay1);
    ax2 = fmaf(n2, bfLo(u2), ax2); ay2 = fmaf(n2, bfHi(u2), ay2);
    ax3 = fmaf(n3, bfLo(u3), ax3); ay3 = fmaf(n3, bfHi(u3), ay3);
    ax0 = fmaf(n4, bfLo(u4), ax0); ay0 = fmaf(n4, bfHi(u4), ay0);
    ax1 = fmaf(n5, bfLo(u5), ax1); ay1 = fmaf(n5, bfHi(u5), ay1);
    ax2 = fmaf(n6, bfLo(u6), ax2); ay2 = fmaf(n6, bfHi(u6), ay2);
    ax3 = fmaf(n7, bfLo(u7), ax3); ay3 = fmaf(n7, bfHi(u7), ay3);
  }
  for (; i < n; ++i) {
    int2 e = edges[start + i];
    float nrm = __int_as_float(e.y);
    uint32_t u = m32[(size_t)e.x * 64 + lane];
    ax0 = fmaf(nrm, bfLo(u), ax0);
    ay0 = fmaf(nrm, bfHi(u), ay0);
  }
  float ax = (ax0 + ax1) + (ax2 + ax3) + bias[2 * lane];
  float ay = (ay0 + ay1) + (ay2 + ay3) + bias[2 * lane + 1];
  ax = fmaxf(ax, 0.f);
  ay = fmaxf(ay, 0.f);
  ushort2 h2;
  h2.x = f2bf(ax);
  h2.y = f2bf(ay);
  ((ushort2*)Hout)[(size_t)v * 64 + lane] = h2;
}

// ---------------- pooled conv3: f_sum = coefT x msg (LDS-chunked) --------
// thread t: graph g = t>>2, features fo=(t&3)*32 .. +31; 32 fp32 accs.
__global__ __launch_bounds__(256) void pool_gemm(const ushort* __restrict__ msg,
                                                 const float* __restrict__ coefT,
                                                 float* __restrict__ f_sum) {
  __shared__ ushort tile[CHUNK * FEAT];   // 64 KB
  int t = threadIdx.x;
  int g = t >> 2;
  int fo = (t & 3) * 32;
  float acc[32];
#pragma unroll
  for (int j = 0; j < 32; ++j) acc[j] = 0.f;
  for (int ci = blockIdx.x; ci * CHUNK < N_NODES; ci += gridDim.x) {
    int c0 = ci * CHUNK;
    int nv = min(CHUNK, N_NODES - c0);
    __syncthreads();
    // stage nv rows (uint4 = 16B per thread per iter)
    const uint4* gsrc = (const uint4*)(msg + (size_t)c0 * FEAT);
    for (int it = 0; it < CHUNK * FEAT / (256 * 8); ++it) {
      int idx = it * 256 + t;          // uint4 index; 16 per row
      if ((idx >> 4) < nv) ((uint4*)tile)[idx] = gsrc[idx];
    }
    __syncthreads();
    const float* crow = coefT + (size_t)g * N_NODES + c0;
    for (int v = 0; v < nv; ++v) {
      float c = crow[v];
      if (c != 0.f) {
        const ushort* mrow = tile + v * FEAT + fo;
#pragma unroll
        for (int j = 0; j < 32; j += 2) {
          uint32_t u = *(const uint32_t*)(mrow + j);
          acc[j]     = fmaf(c, bfLo(u), acc[j]);
          acc[j + 1] = fmaf(c, bfHi(u), acc[j + 1]);
        }
      }
    }
  }
  float* fs = f_sum + g * FEAT + fo;
#pragma unroll
  for (int j = 0; j < 32; ++j) atomicAdd(fs + j, acc[j]);
}

// ---------------- per-graph node counts (LDS binned) ---------------------
__global__ __launch_bounds__(256) void count_graphs(const int* __restrict__ batch,
                                                    float* __restrict__ cnt_g) {
  __shared__ int bins[NGRAPH];
  if (threadIdx.x < NGRAPH) bins[threadIdx.x] = 0;
  __syncthreads();
  int i = blockIdx.x * 256 + threadIdx.x;
  if (i < N_NODES) atomicAdd(&bins[batch[i]], 1);
  __syncthreads();
  if (threadIdx.x < NGRAPH && bins[threadIdx.x] > 0)
    atomicAdd(&cnt_g[threadIdx.x], (float)bins[threadIdx.x]);
}

// ---------------- finalize f = sums/cnt + b3 (fp32, output 0) ------------
__global__ __launch_bounds__(256) void finalize_f(const float* __restrict__ f_sum,
                                                  const float* __restrict__ cnt_g,
                                                  const float* __restrict__ b3,
                                                  float* __restrict__ out_f) {
  int i = blockIdx.x * 256 + threadIdx.x;
  if (i < NGRAPH * FEAT) {
    float c = fmaxf(cnt_g[i >> 7], 1.0f);
    out_f[i] = f_sum[i] / c + b3[i & (FEAT - 1)];
  }
}

// ---------------- FC head: split-K atomic GEMM ---------------------------
__global__ __launch_bounds__(256) void fc_init(const float* __restrict__ b,
                                               float* __restrict__ out, int C) {
  int i = blockIdx.x * 256 + threadIdx.x;
  if (i < NGRAPH * C) out[i] = b[i % C];
}

__global__ __launch_bounds__(256) void fc_accum(const float* __restrict__ in,
                                                const float* __restrict__ w,
                                                float* __restrict__ out,
                                                int K, int C, int relu_in,
                                                int cstrips, int kchunks) {
  int wave = (blockIdx.x * 256 + threadIdx.x) >> 6;
  int lane = threadIdx.x & 63;
  int perrow = cstrips * kchunks;
  int r = wave / perrow;
  if (r >= NGRAPH) return;
  int rem = wave - r * perrow;
  int cs = rem / kchunks;
  int kc = rem - cs * kchunks;
  int c = cs * 64 + lane;
  if (c >= C) return;
  const float* inr = in + (size_t)r * K + kc * 64;
  const float* wp = w + (size_t)(kc * 64) * C + c;
  float a0 = 0.f, a1 = 0.f, a2 = 0.f, a3 = 0.f;
#pragma unroll 4
  for (int k = 0; k < 64; k += 4) {
    float i0 = inr[k], i1 = inr[k + 1], i2 = inr[k + 2], i3 = inr[k + 3];
    if (relu_in) {
      i0 = fmaxf(i0, 0.f); i1 = fmaxf(i1, 0.f);
      i2 = fmaxf(i2, 0.f); i3 = fmaxf(i3, 0.f);
    }
    a0 = fmaf(i0, wp[(size_t)k * C], a0);
    a1 = fmaf(i1, wp[(size_t)(k + 1) * C], a1);
    a2 = fmaf(i2, wp[(size_t)(k + 2) * C], a2);
    a3 = fmaf(i3, wp[(size_t)(k + 3) * C], a3);
  }
  atomicAdd(&out[(size_t)r * C + c], (a0 + a1) + (a2 + a3));
}

static inline void fc_run(const float* in, const float* w, const float* b,
                          float* out, int K, int C, int relu_in,
                          hipStream_t stream) {
  int cstrips = (C + 63) / 64;
  int kchunks = K / 64;
  fc_init<<<(NGRAPH * C + 255) / 256, 256, 0, stream>>>(b, out, C);
  int waves = NGRAPH * cstrips * kchunks;
  fc_accum<<<(waves * 64 + 255) / 256, 256, 0, stream>>>(in, w, out, K, C,
                                                         relu_in, cstrips, kchunks);
}

// =========================================================================
extern "C" void kernel_launch(void* const* d_in, const int* in_sizes, int n_in,
                              void* d_out, int out_size, void* d_ws, size_t ws_size,
                              hipStream_t stream) {
  const float* x         = (const float*)d_in[0];
  const int*   ei        = (const int*)d_in[1];     // [2][E]: row0 src, row1 dst
  const int*   batch     = (const int*)d_in[2];
  const float* conv_w[3] = {(const float*)d_in[3], (const float*)d_in[5], (const float*)d_in[7]};
  const float* conv_b[3] = {(const float*)d_in[4], (const float*)d_in[6], (const float*)d_in[8]};
  const float* fc_w[5]   = {(const float*)d_in[9],  (const float*)d_in[11],
                            (const float*)d_in[13], (const float*)d_in[15],
                            (const float*)d_in[17]};
  const float* fc_b[5]   = {(const float*)d_in[10], (const float*)d_in[12],
                            (const float*)d_in[14], (const float*)d_in[16],
                            (const float*)d_in[18]};
  const int* e_src = ei;
  const int* e_dst = ei + N_EDGES;
  float* out_f = (float*)d_out;                  // [64][128] fp32  (output 0)
  float* out_y = (float*)d_out + NGRAPH * FEAT;  // [64][10]  fp32  (output 1)

  char* p = (char*)d_ws;
  auto carve = [&](size_t bytes) {
    char* r = p;
    p += (bytes + 255) & ~(size_t)255;
    return r;
  };
  int*    cnt_i   = (int*)carve(N_NODES * 4);
  float*  dinv    = (float*)carve(N_NODES * 4);
  int*    csr_ptr = (int*)carve(N_NODES * 4);
  int*    cursor  = (int*)carve(N_NODES * 4);
  int*    bsums   = (int*)carve(256 * 4);
  int2*   edges   = (int2*)carve((size_t)N_EDGES * 8);
  ushort* xb      = (ushort*)carve((size_t)N_NODES * FEAT * 2);   // bf16 x
  ushort* wb      = (ushort*)carve((size_t)3 * FEAT * FEAT * 2);  // bf16 conv weights
  ushort* msl     = (ushort*)carve((size_t)N_NODES * FEAT * 2);   // bf16 messages XW
  ushort* hbuf    = (ushort*)carve((size_t)N_NODES * FEAT * 2);   // bf16 h
  float*  coefT   = (float*)carve((size_t)NGRAPH * N_NODES * 4);  // 12.8 MB
  float*  f_sum   = (float*)carve(NGRAPH * FEAT * 4);
  float*  cnt_g   = (float*)carve(NGRAPH * 4);
  float*  act1    = (float*)carve(NGRAPH * 1024 * 4);
  float*  act2    = (float*)carve(NGRAPH * 512 * 4);
  float*  act3    = (float*)carve(NGRAPH * 256 * 4);
  float*  act4    = (float*)carve(NGRAPH * 128 * 4);

  const int BLK_E = (N_EDGES + 255) / 256;
  const int BLK_N = (N_NODES + 255) / 256;

  hipMemsetAsync(cnt_i, 0, N_NODES * 4, stream);
  hipMemsetAsync(coefT, 0, (size_t)NGRAPH * N_NODES * 4, stream);
  hipMemsetAsync(f_sum, 0, NGRAPH * FEAT * 4, stream);
  hipMemsetAsync(cnt_g, 0, NGRAPH * 4, stream);

  // ---- fp32 -> bf16 prep (x, conv weights) ----
  cvt_bf16<<<(N_NODES * FEAT / 4 + 255) / 256, 256, 0, stream>>>(x, xb, N_NODES * FEAT / 4);
  cvt_bf16<<<(FEAT * FEAT / 4 + 255) / 256, 256, 0, stream>>>(conv_w[0], wb,                   FEAT * FEAT / 4);
  cvt_bf16<<<(FEAT * FEAT / 4 + 255) / 256, 256, 0, stream>>>(conv_w[1], wb + FEAT * FEAT,     FEAT * FEAT / 4);
  cvt_bf16<<<(FEAT * FEAT / 4 + 255) / 256, 256, 0, stream>>>(conv_w[2], wb + 2 * FEAT * FEAT, FEAT * FEAT / 4);

  // ---- build CSR + norms + coefT (reused by all convs / pooled conv3) ----
  count_deg<<<BLK_E, 256, 0, stream>>>(e_dst, cnt_i);
  compute_dinv<<<BLK_N, 256, 0, stream>>>(cnt_i, batch, dinv, coefT);
  scan1<<<BLK_N, 256, 0, stream>>>(cnt_i, csr_ptr, bsums);
  scan2<<<1, 256, 0, stream>>>(bsums, BLK_N);
  scan3<<<BLK_N, 256, 0, stream>>>(csr_ptr, cursor, bsums);
  fill_csr<<<BLK_E, 256, 0, stream>>>(e_src, e_dst, dinv, batch, cursor, edges, coefT);

  const int GEMM_BLKS = (N_NODES / 16) * 8 / 4;
  const int AGG_BLKS  = (N_NODES + 3) / 4;

  // ---- conv1 ----
  gemm128<<<GEMM_BLKS, 256, 0, stream>>>(xb, wb, msl, N_NODES / 16);
  agg_kernel<<<AGG_BLKS, 256, 0, stream>>>(msl, dinv, csr_ptr, cnt_i, edges,
                                           conv_b[0], hbuf);
  // ---- conv2 ----
  gemm128<<<GEMM_BLKS, 256, 0, stream>>>(hbuf, wb + FEAT * FEAT, msl, N_NODES / 16);
  agg_kernel<<<AGG_BLKS, 256, 0, stream>>>(msl, dinv, csr_ptr, cnt_i, edges,
                                           conv_b[1], hbuf);
  // ---- conv3: GEMM then pooled aggregation (no per-node gather) ----
  gemm128<<<GEMM_BLKS, 256, 0, stream>>>(hbuf, wb + 2 * FEAT * FEAT, msl, N_NODES / 16);
  pool_gemm<<<98, 256, 0, stream>>>(msl, coefT, f_sum);

  // ---- pool ----
  count_graphs<<<BLK_N, 256, 0, stream>>>(batch, cnt_g);
  finalize_f<<<(NGRAPH * FEAT + 255) / 256, 256, 0, stream>>>(f_sum, cnt_g,
                                                              conv_b[2], out_f);

  // ---- FC head: split-K atomic GEMMs, relu fused into next layer's read ----
  fc_run(out_f, fc_w[0], fc_b[0], act1, 128, 1024, 0, stream);
  fc_run(act1,  fc_w[1], fc_b[1], act2, 1024, 512, 1, stream);
  fc_run(act2,  fc_w[2], fc_b[2], act3, 512, 256, 1, stream);
  fc_run(act3,  fc_w[3], fc_b[3], act4, 256, 128, 1, stream);
  fc_run(act4,  fc_w[4], fc_b[4], out_y, 128, 10, 1, stream);
}

// Round 9
// 630.060 us; speedup vs baseline: 1.4585x; 1.0090x over previous
//
#include <hip/hip_runtime.h>
#include <stdint.h>

#define N_NODES 50000
#define N_EDGES 800000
#define FEAT    128
#define NGRAPH  64
#define PCHUNK  512      // pool_gemm nodes per wave-chunk
#define NCHUNKS ((N_NODES + PCHUNK - 1) / PCHUNK)   // 98

typedef __attribute__((ext_vector_type(8))) short short8;
typedef __attribute__((ext_vector_type(4))) float floatx4;

static __device__ __forceinline__ ushort f2bf(float f) {
  uint32_t x = __float_as_uint(f);
  x += 0x7FFF + ((x >> 16) & 1);   // RNE
  return (ushort)(x >> 16);
}
static __device__ __forceinline__ float bfLo(uint32_t u) {
  return __uint_as_float(u << 16);
}
static __device__ __forceinline__ float bfHi(uint32_t u) {
  return __uint_as_float(u & 0xFFFF0000u);
}

// ---------------- fp32 -> bf16 row-major ---------------------------------
__global__ __launch_bounds__(256) void cvt_bf16(const float* __restrict__ in,
                                                ushort* __restrict__ out, int n4) {
  int i = blockIdx.x * 256 + threadIdx.x;
  if (i >= n4) return;
  float4 v = ((const float4*)in)[i];
  ushort4 u;
  u.x = f2bf(v.x); u.y = f2bf(v.y); u.z = f2bf(v.z); u.w = f2bf(v.w);
  ((ushort4*)out)[i] = u;
}

// ---------------- degree count -------------------------------------------
__global__ __launch_bounds__(256) void count_deg(const int* __restrict__ dst,
                                                 int* __restrict__ cnt) {
  int e = blockIdx.x * 256 + threadIdx.x;
  if (e < N_EDGES) atomicAdd(&cnt[dst[e]], 1);
}

// dinv + self-loop coef term (plain store into zeroed coefT)
__global__ __launch_bounds__(256) void compute_dinv(const int* __restrict__ cnt,
                                                    const int* __restrict__ batch,
                                                    float* __restrict__ dinv,
                                                    float* __restrict__ coefT) {
  int i = blockIdx.x * 256 + threadIdx.x;
  if (i < N_NODES) {
    float di = rsqrtf((float)cnt[i] + 1.0f);
    dinv[i] = di;
    coefT[(size_t)batch[i] * N_NODES + i] = di * di;
  }
}

// ---------------- exclusive scan (3 kernels) -----------------------------
__global__ __launch_bounds__(256) void scan1(const int* __restrict__ cnt,
                                             int* __restrict__ ptr,
                                             int* __restrict__ bsums) {
  __shared__ int tmp[256];
  int i = blockIdx.x * 256 + threadIdx.x;
  int v = (i < N_NODES) ? cnt[i] : 0;
  tmp[threadIdx.x] = v;
  __syncthreads();
  for (int off = 1; off < 256; off <<= 1) {
    int t = (threadIdx.x >= off) ? tmp[threadIdx.x - off] : 0;
    __syncthreads();
    tmp[threadIdx.x] += t;
    __syncthreads();
  }
  if (i < N_NODES) ptr[i] = tmp[threadIdx.x] - v;           // exclusive
  if (threadIdx.x == 255) bsums[blockIdx.x] = tmp[255];
}

__global__ __launch_bounds__(256) void scan2(int* __restrict__ bsums, int nb) {
  __shared__ int tmp[256];
  int v = (threadIdx.x < nb) ? bsums[threadIdx.x] : 0;
  tmp[threadIdx.x] = v;
  __syncthreads();
  for (int off = 1; off < 256; off <<= 1) {
    int t = (threadIdx.x >= off) ? tmp[threadIdx.x - off] : 0;
    __syncthreads();
    tmp[threadIdx.x] += t;
    __syncthreads();
  }
  if (threadIdx.x < nb) bsums[threadIdx.x] = tmp[threadIdx.x] - v;  // exclusive
}

__global__ __launch_bounds__(256) void scan3(int* __restrict__ ptr,
                                             int* __restrict__ cursor,
                                             const int* __restrict__ bsums) {
  int i = blockIdx.x * 256 + threadIdx.x;
  if (i < N_NODES) {
    int p = ptr[i] + bsums[blockIdx.x];
    ptr[i] = p;
    cursor[i] = p;
  }
}

// ---------------- CSR fill (src + fused norm) + coef edge terms ----------
__global__ __launch_bounds__(256) void fill_csr(const int* __restrict__ src,
                                                const int* __restrict__ dst,
                                                const float* __restrict__ dinv,
                                                const int* __restrict__ batch,
                                                int* __restrict__ cursor,
                                                int2* __restrict__ edges,
                                                float* __restrict__ coefT) {
  int e = blockIdx.x * 256 + threadIdx.x;
  if (e >= N_EDGES) return;
  int s = src[e], d = dst[e];
  int pos = atomicAdd(&cursor[d], 1);
  float nrm = dinv[s] * dinv[d];
  edges[pos] = make_int2(s, __float_as_int(nrm));
  atomicAdd(&coefT[(size_t)batch[d] * N_NODES + s], nrm);
}

// ---------------- GEMM [M,128] x [128,128] via MFMA bf16, bf16 out -------
__global__ __launch_bounds__(256) void gemm128(const ushort* __restrict__ X,
                                               const ushort* __restrict__ W,
                                               ushort* __restrict__ XW,
                                               int nTilesM) {
  int wave = (blockIdx.x * 256 + threadIdx.x) >> 6;
  int lane = threadIdx.x & 63;
  int mt = wave >> 3;  // 8 n-tiles per m-tile
  int nt = wave & 7;
  if (mt >= nTilesM) return;
  int m0 = mt * 16, n0 = nt * 16;
  int r = lane & 15, quad = lane >> 4;
  floatx4 acc = {0.f, 0.f, 0.f, 0.f};
  const ushort* xrow = X + (size_t)(m0 + r) * FEAT;
#pragma unroll
  for (int kb = 0; kb < 4; ++kb) {
    int k0 = kb * 32 + quad * 8;
    short8 a = *(const short8*)(xrow + k0);
    short8 b;
#pragma unroll
    for (int j = 0; j < 8; ++j) b[j] = (short)W[(size_t)(k0 + j) * FEAT + n0 + r];
    acc = __builtin_amdgcn_mfma_f32_16x16x32_bf16(a, b, acc, 0, 0, 0);
  }
#pragma unroll
  for (int reg = 0; reg < 4; ++reg) {
    int row = quad * 4 + reg;
    XW[(size_t)(m0 + row) * FEAT + n0 + r] = f2bf(acc[reg]);
  }
}

// ---------------- aggregation (r6 proven): wave/node, 8-edge ILP ---------
__global__ __launch_bounds__(256) void agg_kernel(const ushort* __restrict__ msg,
                                                  const float* __restrict__ dinv,
                                                  const int* __restrict__ ptr,
                                                  const int* __restrict__ cnt,
                                                  const int2* __restrict__ edges,
                                                  const float* __restrict__ bias,
                                                  ushort* __restrict__ Hout) {
  int wave = (blockIdx.x * 256 + threadIdx.x) >> 6;
  int lane = threadIdx.x & 63;
  if (wave >= N_NODES) return;
  int v = wave;
  float di = dinv[v];
  const uint32_t* m32 = (const uint32_t*)msg;   // 64 dwords per node row
  uint32_t su = m32[(size_t)v * 64 + lane];
  float sn = di * di;
  float ax0 = bfLo(su) * sn, ay0 = bfHi(su) * sn;
  float ax1 = 0.f, ay1 = 0.f, ax2 = 0.f, ay2 = 0.f, ax3 = 0.f, ay3 = 0.f;
  int start = ptr[v];
  int n = cnt[v];
  int i = 0;
  if ((start & 1) && n > 0) {
    int2 e = edges[start];
    uint32_t u = m32[(size_t)e.x * 64 + lane];
    float nrm = __int_as_float(e.y);
    ax0 = fmaf(nrm, bfLo(u), ax0);
    ay0 = fmaf(nrm, bfHi(u), ay0);
    i = 1;
  }
  for (; i + 8 <= n; i += 8) {
    const int4* ep = (const int4*)(edges + start + i);   // 16B-aligned
    int4 q0 = ep[0], q1 = ep[1], q2 = ep[2], q3 = ep[3];
    uint32_t u0 = m32[(size_t)q0.x * 64 + lane];
    uint32_t u1 = m32[(size_t)q0.z * 64 + lane];
    uint32_t u2 = m32[(size_t)q1.x * 64 + lane];
    uint32_t u3 = m32[(size_t)q1.z * 64 + lane];
    uint32_t u4 = m32[(size_t)q2.x * 64 + lane];
    uint32_t u5 = m32[(size_t)q2.z * 64 + lane];
    uint32_t u6 = m32[(size_t)q3.x * 64 + lane];
    uint32_t u7 = m32[(size_t)q3.z * 64 + lane];
    float n0 = __int_as_float(q0.y), n1 = __int_as_float(q0.w);
    float n2 = __int_as_float(q1.y), n3 = __int_as_float(q1.w);
    float n4 = __int_as_float(q2.y), n5 = __int_as_float(q2.w);
    float n6 = __int_as_float(q3.y), n7 = __int_as_float(q3.w);
    ax0 = fmaf(n0, bfLo(u0), ax0); ay0 = fmaf(n0, bfHi(u0), ay0);
    ax1 = fmaf(n1, bfLo(u1), ax1); ay1 = fmaf(n1, bfHi(u1), ay1);
    ax2 = fmaf(n2, bfLo(u2), ax2); ay2 = fmaf(n2, bfHi(u2), ay2);
    ax3 = fmaf(n3, bfLo(u3), ax3); ay3 = fmaf(n3, bfHi(u3), ay3);
    ax0 = fmaf(n4, bfLo(u4), ax0); ay0 = fmaf(n4, bfHi(u4), ay0);
    ax1 = fmaf(n5, bfLo(u5), ax1); ay1 = fmaf(n5, bfHi(u5), ay1);
    ax2 = fmaf(n6, bfLo(u6), ax2); ay2 = fmaf(n6, bfHi(u6), ay2);
    ax3 = fmaf(n7, bfLo(u7), ax3); ay3 = fmaf(n7, bfHi(u7), ay3);
  }
  for (; i < n; ++i) {
    int2 e = edges[start + i];
    float nrm = __int_as_float(e.y);
    uint32_t u = m32[(size_t)e.x * 64 + lane];
    ax0 = fmaf(nrm, bfLo(u), ax0);
    ay0 = fmaf(nrm, bfHi(u), ay0);
  }
  float ax = (ax0 + ax1) + (ax2 + ax3) + bias[2 * lane];
  float ay = (ay0 + ay1) + (ay2 + ay3) + bias[2 * lane + 1];
  ax = fmaxf(ax, 0.f);
  ay = fmaxf(ay, 0.f);
  ushort2 h2;
  h2.x = f2bf(ax);
  h2.y = f2bf(ay);
  ((ushort2*)Hout)[(size_t)v * 64 + lane] = h2;
}

// ---------------- pooled conv3: f_sum = coefT x msg, ordered scan --------
// wave w: graph g = w & 63, K-chunk ck = w >> 6 (512 nodes, ascending).
// lane = dword column (full 256B coalesced row reads). coef is wave-uniform
// -> readfirstlane + scalar branch skips zero-coef rows (~74%).
__global__ __launch_bounds__(256) void pool_gemm(const ushort* __restrict__ msg,
                                                 const float* __restrict__ coefT,
                                                 float* __restrict__ f_sum) {
  int w = (blockIdx.x * 256 + threadIdx.x) >> 6;
  int lane = threadIdx.x & 63;
  int g = w & 63;
  int ck = w >> 6;
  if (ck >= NCHUNKS) return;
  int c0 = ck * PCHUNK;
  int nv = min(PCHUNK, N_NODES - c0);
  const float* crow = coefT + (size_t)g * N_NODES + c0;
  const uint32_t* m32 = (const uint32_t*)msg + (size_t)c0 * 64 + lane;
  float ax = 0.f, ay = 0.f;
#pragma unroll 4
  for (int v = 0; v < nv; ++v) {
    float c = __int_as_float(
        __builtin_amdgcn_readfirstlane(__float_as_int(crow[v])));
    if (c != 0.f) {
      uint32_t u = m32[(size_t)v * 64];
      ax = fmaf(c, bfLo(u), ax);
      ay = fmaf(c, bfHi(u), ay);
    }
  }
  float* fs = f_sum + g * FEAT + 2 * lane;
  atomicAdd(fs, ax);
  atomicAdd(fs + 1, ay);
}

// ---------------- per-graph node counts (LDS binned) ---------------------
__global__ __launch_bounds__(256) void count_graphs(const int* __restrict__ batch,
                                                    float* __restrict__ cnt_g) {
  __shared__ int bins[NGRAPH];
  if (threadIdx.x < NGRAPH) bins[threadIdx.x] = 0;
  __syncthreads();
  int i = blockIdx.x * 256 + threadIdx.x;
  if (i < N_NODES) atomicAdd(&bins[batch[i]], 1);
  __syncthreads();
  if (threadIdx.x < NGRAPH && bins[threadIdx.x] > 0)
    atomicAdd(&cnt_g[threadIdx.x], (float)bins[threadIdx.x]);
}

// ---------------- finalize f = sums/cnt + b3 (fp32, output 0) ------------
__global__ __launch_bounds__(256) void finalize_f(const float* __restrict__ f_sum,
                                                  const float* __restrict__ cnt_g,
                                                  const float* __restrict__ b3,
                                                  float* __restrict__ out_f) {
  int i = blockIdx.x * 256 + threadIdx.x;
  if (i < NGRAPH * FEAT) {
    float c = fmaxf(cnt_g[i >> 7], 1.0f);
    out_f[i] = f_sum[i] / c + b3[i & (FEAT - 1)];
  }
}

// ---------------- FC head: split-K atomic GEMM ---------------------------
__global__ __launch_bounds__(256) void fc_init(const float* __restrict__ b,
                                               float* __restrict__ out, int C) {
  int i = blockIdx.x * 256 + threadIdx.x;
  if (i < NGRAPH * C) out[i] = b[i % C];
}

__global__ __launch_bounds__(256) void fc_accum(const float* __restrict__ in,
                                                const float* __restrict__ w,
                                                float* __restrict__ out,
                                                int K, int C, int relu_in,
                                                int cstrips, int kchunks) {
  int wave = (blockIdx.x * 256 + threadIdx.x) >> 6;
  int lane = threadIdx.x & 63;
  int perrow = cstrips * kchunks;
  int r = wave / perrow;
  if (r >= NGRAPH) return;
  int rem = wave - r * perrow;
  int cs = rem / kchunks;
  int kc = rem - cs * kchunks;
  int c = cs * 64 + lane;
  if (c >= C) return;
  const float* inr = in + (size_t)r * K + kc * 64;
  const float* wp = w + (size_t)(kc * 64) * C + c;
  float a0 = 0.f, a1 = 0.f, a2 = 0.f, a3 = 0.f;
#pragma unroll 4
  for (int k = 0; k < 64; k += 4) {
    float i0 = inr[k], i1 = inr[k + 1], i2 = inr[k + 2], i3 = inr[k + 3];
    if (relu_in) {
      i0 = fmaxf(i0, 0.f); i1 = fmaxf(i1, 0.f);
      i2 = fmaxf(i2, 0.f); i3 = fmaxf(i3, 0.f);
    }
    a0 = fmaf(i0, wp[(size_t)k * C], a0);
    a1 = fmaf(i1, wp[(size_t)(k + 1) * C], a1);
    a2 = fmaf(i2, wp[(size_t)(k + 2) * C], a2);
    a3 = fmaf(i3, wp[(size_t)(k + 3) * C], a3);
  }
  atomicAdd(&out[(size_t)r * C + c], (a0 + a1) + (a2 + a3));
}

static inline void fc_run(const float* in, const float* w, const float* b,
                          float* out, int K, int C, int relu_in,
                          hipStream_t stream) {
  int cstrips = (C + 63) / 64;
  int kchunks = K / 64;
  fc_init<<<(NGRAPH * C + 255) / 256, 256, 0, stream>>>(b, out, C);
  int waves = NGRAPH * cstrips * kchunks;
  fc_accum<<<(waves * 64 + 255) / 256, 256, 0, stream>>>(in, w, out, K, C,
                                                         relu_in, cstrips, kchunks);
}

// =========================================================================
extern "C" void kernel_launch(void* const* d_in, const int* in_sizes, int n_in,
                              void* d_out, int out_size, void* d_ws, size_t ws_size,
                              hipStream_t stream) {
  const float* x         = (const float*)d_in[0];
  const int*   ei        = (const int*)d_in[1];     // [2][E]: row0 src, row1 dst
  const int*   batch     = (const int*)d_in[2];
  const float* conv_w[3] = {(const float*)d_in[3], (const float*)d_in[5], (const float*)d_in[7]};
  const float* conv_b[3] = {(const float*)d_in[4], (const float*)d_in[6], (const float*)d_in[8]};
  const float* fc_w[5]   = {(const float*)d_in[9],  (const float*)d_in[11],
                            (const float*)d_in[13], (const float*)d_in[15],
                            (const float*)d_in[17]};
  const float* fc_b[5]   = {(const float*)d_in[10], (const float*)d_in[12],
                            (const float*)d_in[14], (const float*)d_in[16],
                            (const float*)d_in[18]};
  const int* e_src = ei;
  const int* e_dst = ei + N_EDGES;
  float* out_f = (float*)d_out;                  // [64][128] fp32  (output 0)
  float* out_y = (float*)d_out + NGRAPH * FEAT;  // [64][10]  fp32  (output 1)

  char* p = (char*)d_ws;
  auto carve = [&](size_t bytes) {
    char* r = p;
    p += (bytes + 255) & ~(size_t)255;
    return r;
  };
  int*    cnt_i   = (int*)carve(N_NODES * 4);
  float*  dinv    = (float*)carve(N_NODES * 4);
  int*    csr_ptr = (int*)carve(N_NODES * 4);
  int*    cursor  = (int*)carve(N_NODES * 4);
  int*    bsums   = (int*)carve(256 * 4);
  int2*   edges   = (int2*)carve((size_t)N_EDGES * 8);
  ushort* xb      = (ushort*)carve((size_t)N_NODES * FEAT * 2);   // bf16 x
  ushort* wb      = (ushort*)carve((size_t)3 * FEAT * FEAT * 2);  // bf16 conv weights
  ushort* msl     = (ushort*)carve((size_t)N_NODES * FEAT * 2);   // bf16 messages XW
  ushort* hbuf    = (ushort*)carve((size_t)N_NODES * FEAT * 2);   // bf16 h
  float*  coefT   = (float*)carve((size_t)NGRAPH * N_NODES * 4);  // 12.8 MB
  float*  f_sum   = (float*)carve(NGRAPH * FEAT * 4);
  float*  cnt_g   = (float*)carve(NGRAPH * 4);
  float*  act1    = (float*)carve(NGRAPH * 1024 * 4);
  float*  act2    = (float*)carve(NGRAPH * 512 * 4);
  float*  act3    = (float*)carve(NGRAPH * 256 * 4);
  float*  act4    = (float*)carve(NGRAPH * 128 * 4);

  const int BLK_E = (N_EDGES + 255) / 256;
  const int BLK_N = (N_NODES + 255) / 256;

  hipMemsetAsync(cnt_i, 0, N_NODES * 4, stream);
  hipMemsetAsync(coefT, 0, (size_t)NGRAPH * N_NODES * 4, stream);
  hipMemsetAsync(f_sum, 0, NGRAPH * FEAT * 4, stream);
  hipMemsetAsync(cnt_g, 0, NGRAPH * 4, stream);

  // ---- fp32 -> bf16 prep (x, conv weights) ----
  cvt_bf16<<<(N_NODES * FEAT / 4 + 255) / 256, 256, 0, stream>>>(x, xb, N_NODES * FEAT / 4);
  cvt_bf16<<<(FEAT * FEAT / 4 + 255) / 256, 256, 0, stream>>>(conv_w[0], wb,                   FEAT * FEAT / 4);
  cvt_bf16<<<(FEAT * FEAT / 4 + 255) / 256, 256, 0, stream>>>(conv_w[1], wb + FEAT * FEAT,     FEAT * FEAT / 4);
  cvt_bf16<<<(FEAT * FEAT / 4 + 255) / 256, 256, 0, stream>>>(conv_w[2], wb + 2 * FEAT * FEAT, FEAT * FEAT / 4);

  // ---- build CSR + norms + coefT ----
  count_deg<<<BLK_E, 256, 0, stream>>>(e_dst, cnt_i);
  compute_dinv<<<BLK_N, 256, 0, stream>>>(cnt_i, batch, dinv, coefT);
  scan1<<<BLK_N, 256, 0, stream>>>(cnt_i, csr_ptr, bsums);
  scan2<<<1, 256, 0, stream>>>(bsums, BLK_N);
  scan3<<<BLK_N, 256, 0, stream>>>(csr_ptr, cursor, bsums);
  fill_csr<<<BLK_E, 256, 0, stream>>>(e_src, e_dst, dinv, batch, cursor, edges, coefT);

  const int GEMM_BLKS = (N_NODES / 16) * 8 / 4;
  const int AGG_BLKS  = (N_NODES + 3) / 4;
  const int POOL_BLKS = (NCHUNKS * NGRAPH) / 4;   // 1568

  // ---- conv1 ----
  gemm128<<<GEMM_BLKS, 256, 0, stream>>>(xb, wb, msl, N_NODES / 16);
  agg_kernel<<<AGG_BLKS, 256, 0, stream>>>(msl, dinv, csr_ptr, cnt_i, edges,
                                           conv_b[0], hbuf);
  // ---- conv2 ----
  gemm128<<<GEMM_BLKS, 256, 0, stream>>>(hbuf, wb + FEAT * FEAT, msl, N_NODES / 16);
  agg_kernel<<<AGG_BLKS, 256, 0, stream>>>(msl, dinv, csr_ptr, cnt_i, edges,
                                           conv_b[1], hbuf);
  // ---- conv3: GEMM then pooled ordered-scan aggregation ----
  gemm128<<<GEMM_BLKS, 256, 0, stream>>>(hbuf, wb + 2 * FEAT * FEAT, msl, N_NODES / 16);
  pool_gemm<<<POOL_BLKS, 256, 0, stream>>>(msl, coefT, f_sum);

  // ---- pool ----
  count_graphs<<<BLK_N, 256, 0, stream>>>(batch, cnt_g);
  finalize_f<<<(NGRAPH * FEAT + 255) / 256, 256, 0, stream>>>(f_sum, cnt_g,
                                                              conv_b[2], out_f);

  // ---- FC head: split-K atomic GEMMs, relu fused into next layer's read ----
  fc_run(out_f, fc_w[0], fc_b[0], act1, 128, 1024, 0, stream);
  fc_run(act1,  fc_w[1], fc_b[1], act2, 1024, 512, 1, stream);
  fc_run(act2,  fc_w[2], fc_b[2], act3, 512, 256, 1, stream);
  fc_run(act3,  fc_w[3], fc_b[3], act4, 256, 128, 1, stream);
  fc_run(act4,  fc_w[4], fc_b[4], out_y, 128, 10, 1, stream);
}

// Round 10
// 499.439 us; speedup vs baseline: 1.8399x; 1.2615x over previous
//
#include <hip/hip_runtime.h>
#include <stdint.h>

#define N_NODES 50000
#define N_EDGES 800000
#define FEAT    128
#define NGRAPH  64
#define PCHUNK  512      // pool_gemm nodes per wave-chunk
#define NCHUNKS ((N_NODES + PCHUNK - 1) / PCHUNK)   // 98

typedef __attribute__((ext_vector_type(8))) short short8;
typedef __attribute__((ext_vector_type(4))) float floatx4;

static __device__ __forceinline__ ushort f2bf(float f) {
  uint32_t x = __float_as_uint(f);
  x += 0x7FFF + ((x >> 16) & 1);   // RNE
  return (ushort)(x >> 16);
}
static __device__ __forceinline__ float bfLo(uint32_t u) {
  return __uint_as_float(u << 16);
}
static __device__ __forceinline__ float bfHi(uint32_t u) {
  return __uint_as_float(u & 0xFFFF0000u);
}

// ---------------- fp32 -> bf16 row-major ---------------------------------
__global__ __launch_bounds__(256) void cvt_bf16(const float* __restrict__ in,
                                                ushort* __restrict__ out, int n4) {
  int i = blockIdx.x * 256 + threadIdx.x;
  if (i >= n4) return;
  float4 v = ((const float4*)in)[i];
  ushort4 u;
  u.x = f2bf(v.x); u.y = f2bf(v.y); u.z = f2bf(v.z); u.w = f2bf(v.w);
  ((ushort4*)out)[i] = u;
}

// ---------------- degree count -------------------------------------------
__global__ __launch_bounds__(256) void count_deg(const int* __restrict__ dst,
                                                 int* __restrict__ cnt) {
  int e = blockIdx.x * 256 + threadIdx.x;
  if (e < N_EDGES) atomicAdd(&cnt[dst[e]], 1);
}

// dinv + self-loop coef term (plain store into zeroed coefT)
__global__ __launch_bounds__(256) void compute_dinv(const int* __restrict__ cnt,
                                                    const int* __restrict__ batch,
                                                    float* __restrict__ dinv,
                                                    float* __restrict__ coefT) {
  int i = blockIdx.x * 256 + threadIdx.x;
  if (i < N_NODES) {
    float di = rsqrtf((float)cnt[i] + 1.0f);
    dinv[i] = di;
    coefT[(size_t)batch[i] * N_NODES + i] = di * di;
  }
}

// ---------------- exclusive scan (3 kernels) -----------------------------
__global__ __launch_bounds__(256) void scan1(const int* __restrict__ cnt,
                                             int* __restrict__ ptr,
                                             int* __restrict__ bsums) {
  __shared__ int tmp[256];
  int i = blockIdx.x * 256 + threadIdx.x;
  int v = (i < N_NODES) ? cnt[i] : 0;
  tmp[threadIdx.x] = v;
  __syncthreads();
  for (int off = 1; off < 256; off <<= 1) {
    int t = (threadIdx.x >= off) ? tmp[threadIdx.x - off] : 0;
    __syncthreads();
    tmp[threadIdx.x] += t;
    __syncthreads();
  }
  if (i < N_NODES) ptr[i] = tmp[threadIdx.x] - v;           // exclusive
  if (threadIdx.x == 255) bsums[blockIdx.x] = tmp[255];
}

__global__ __launch_bounds__(256) void scan2(int* __restrict__ bsums, int nb) {
  __shared__ int tmp[256];
  int v = (threadIdx.x < nb) ? bsums[threadIdx.x] : 0;
  tmp[threadIdx.x] = v;
  __syncthreads();
  for (int off = 1; off < 256; off <<= 1) {
    int t = (threadIdx.x >= off) ? tmp[threadIdx.x - off] : 0;
    __syncthreads();
    tmp[threadIdx.x] += t;
    __syncthreads();
  }
  if (threadIdx.x < nb) bsums[threadIdx.x] = tmp[threadIdx.x] - v;  // exclusive
}

__global__ __launch_bounds__(256) void scan3(int* __restrict__ ptr,
                                             int* __restrict__ cursor,
                                             const int* __restrict__ bsums) {
  int i = blockIdx.x * 256 + threadIdx.x;
  if (i < N_NODES) {
    int p = ptr[i] + bsums[blockIdx.x];
    ptr[i] = p;
    cursor[i] = p;
  }
}

// ---------------- CSR fill (src + fused norm) + coef edge terms ----------
__global__ __launch_bounds__(256) void fill_csr(const int* __restrict__ src,
                                                const int* __restrict__ dst,
                                                const float* __restrict__ dinv,
                                                const int* __restrict__ batch,
                                                int* __restrict__ cursor,
                                                int2* __restrict__ edges,
                                                float* __restrict__ coefT) {
  int e = blockIdx.x * 256 + threadIdx.x;
  if (e >= N_EDGES) return;
  int s = src[e], d = dst[e];
  int pos = atomicAdd(&cursor[d], 1);
  float nrm = dinv[s] * dinv[d];
  edges[pos] = make_int2(s, __float_as_int(nrm));
  atomicAdd(&coefT[(size_t)batch[d] * N_NODES + s], nrm);
}

// ---------------- GEMM [M,128] x [128,128] via MFMA bf16, bf16 out -------
__global__ __launch_bounds__(256) void gemm128(const ushort* __restrict__ X,
                                               const ushort* __restrict__ W,
                                               ushort* __restrict__ XW,
                                               int nTilesM) {
  int wave = (blockIdx.x * 256 + threadIdx.x) >> 6;
  int lane = threadIdx.x & 63;
  int mt = wave >> 3;  // 8 n-tiles per m-tile
  int nt = wave & 7;
  if (mt >= nTilesM) return;
  int m0 = mt * 16, n0 = nt * 16;
  int r = lane & 15, quad = lane >> 4;
  floatx4 acc = {0.f, 0.f, 0.f, 0.f};
  const ushort* xrow = X + (size_t)(m0 + r) * FEAT;
#pragma unroll
  for (int kb = 0; kb < 4; ++kb) {
    int k0 = kb * 32 + quad * 8;
    short8 a = *(const short8*)(xrow + k0);
    short8 b;
#pragma unroll
    for (int j = 0; j < 8; ++j) b[j] = (short)W[(size_t)(k0 + j) * FEAT + n0 + r];
    acc = __builtin_amdgcn_mfma_f32_16x16x32_bf16(a, b, acc, 0, 0, 0);
  }
#pragma unroll
  for (int reg = 0; reg < 4; ++reg) {
    int row = quad * 4 + reg;
    XW[(size_t)(m0 + row) * FEAT + n0 + r] = f2bf(acc[reg]);
  }
}

// ---------------- aggregation (r6 proven): wave/node, 8-edge ILP ---------
__global__ __launch_bounds__(256) void agg_kernel(const ushort* __restrict__ msg,
                                                  const float* __restrict__ dinv,
                                                  const int* __restrict__ ptr,
                                                  const int* __restrict__ cnt,
                                                  const int2* __restrict__ edges,
                                                  const float* __restrict__ bias,
                                                  ushort* __restrict__ Hout) {
  int wave = (blockIdx.x * 256 + threadIdx.x) >> 6;
  int lane = threadIdx.x & 63;
  if (wave >= N_NODES) return;
  int v = wave;
  float di = dinv[v];
  const uint32_t* m32 = (const uint32_t*)msg;   // 64 dwords per node row
  uint32_t su = m32[(size_t)v * 64 + lane];
  float sn = di * di;
  float ax0 = bfLo(su) * sn, ay0 = bfHi(su) * sn;
  float ax1 = 0.f, ay1 = 0.f, ax2 = 0.f, ay2 = 0.f, ax3 = 0.f, ay3 = 0.f;
  int start = ptr[v];
  int n = cnt[v];
  int i = 0;
  if ((start & 1) && n > 0) {
    int2 e = edges[start];
    uint32_t u = m32[(size_t)e.x * 64 + lane];
    float nrm = __int_as_float(e.y);
    ax0 = fmaf(nrm, bfLo(u), ax0);
    ay0 = fmaf(nrm, bfHi(u), ay0);
    i = 1;
  }
  for (; i + 8 <= n; i += 8) {
    const int4* ep = (const int4*)(edges + start + i);   // 16B-aligned
    int4 q0 = ep[0], q1 = ep[1], q2 = ep[2], q3 = ep[3];
    uint32_t u0 = m32[(size_t)q0.x * 64 + lane];
    uint32_t u1 = m32[(size_t)q0.z * 64 + lane];
    uint32_t u2 = m32[(size_t)q1.x * 64 + lane];
    uint32_t u3 = m32[(size_t)q1.z * 64 + lane];
    uint32_t u4 = m32[(size_t)q2.x * 64 + lane];
    uint32_t u5 = m32[(size_t)q2.z * 64 + lane];
    uint32_t u6 = m32[(size_t)q3.x * 64 + lane];
    uint32_t u7 = m32[(size_t)q3.z * 64 + lane];
    float n0 = __int_as_float(q0.y), n1 = __int_as_float(q0.w);
    float n2 = __int_as_float(q1.y), n3 = __int_as_float(q1.w);
    float n4 = __int_as_float(q2.y), n5 = __int_as_float(q2.w);
    float n6 = __int_as_float(q3.y), n7 = __int_as_float(q3.w);
    ax0 = fmaf(n0, bfLo(u0), ax0); ay0 = fmaf(n0, bfHi(u0), ay0);
    ax1 = fmaf(n1, bfLo(u1), ax1); ay1 = fmaf(n1, bfHi(u1), ay1);
    ax2 = fmaf(n2, bfLo(u2), ax2); ay2 = fmaf(n2, bfHi(u2), ay2);
    ax3 = fmaf(n3, bfLo(u3), ax3); ay3 = fmaf(n3, bfHi(u3), ay3);
    ax0 = fmaf(n4, bfLo(u4), ax0); ay0 = fmaf(n4, bfHi(u4), ay0);
    ax1 = fmaf(n5, bfLo(u5), ax1); ay1 = fmaf(n5, bfHi(u5), ay1);
    ax2 = fmaf(n6, bfLo(u6), ax2); ay2 = fmaf(n6, bfHi(u6), ay2);
    ax3 = fmaf(n7, bfLo(u7), ax3); ay3 = fmaf(n7, bfHi(u7), ay3);
  }
  for (; i < n; ++i) {
    int2 e = edges[start + i];
    float nrm = __int_as_float(e.y);
    uint32_t u = m32[(size_t)e.x * 64 + lane];
    ax0 = fmaf(nrm, bfLo(u), ax0);
    ay0 = fmaf(nrm, bfHi(u), ay0);
  }
  float ax = (ax0 + ax1) + (ax2 + ax3) + bias[2 * lane];
  float ay = (ay0 + ay1) + (ay2 + ay3) + bias[2 * lane + 1];
  ax = fmaxf(ax, 0.f);
  ay = fmaxf(ay, 0.f);
  ushort2 h2;
  h2.x = f2bf(ax);
  h2.y = f2bf(ay);
  ((ushort2*)Hout)[(size_t)v * 64 + lane] = h2;
}

// ---------------- pool v3: P = coefT x h2, 8-wide predicated ILP ---------
// wave w: window ck = w>>6 (consecutive waves share window), graph g = w&63.
// Per 8 nodes: two uniform float4 coef loads, 8 zero-init predicated row
// loads issued before any use (ILP), then 16 unconditional FMAs (c=0 skips).
__global__ __launch_bounds__(256) void pool_gemm(const ushort* __restrict__ h2,
                                                 const float* __restrict__ coefT,
                                                 float* __restrict__ P) {
  int w = (blockIdx.x * 256 + threadIdx.x) >> 6;
  int lane = threadIdx.x & 63;
  int g = w & 63;
  int ck = w >> 6;
  if (ck >= NCHUNKS) return;
  int c0 = ck * PCHUNK;
  int nv = min(PCHUNK, N_NODES - c0);            // 512, last chunk 336 (8|336)
  const float* crow = coefT + (size_t)g * N_NODES + c0;
  const uint32_t* m32 = (const uint32_t*)h2 + (size_t)c0 * 64 + lane;
  float ax = 0.f, ay = 0.f;
  for (int v = 0; v + 8 <= nv; v += 8) {
    float4 ca = *(const float4*)(crow + v);
    float4 cb = *(const float4*)(crow + v + 4);
    uint32_t u0 = 0, u1 = 0, u2 = 0, u3 = 0, u4 = 0, u5 = 0, u6 = 0, u7 = 0;
    if (__builtin_amdgcn_readfirstlane(__float_as_int(ca.x))) u0 = m32[(size_t)(v + 0) * 64];
    if (__builtin_amdgcn_readfirstlane(__float_as_int(ca.y))) u1 = m32[(size_t)(v + 1) * 64];
    if (__builtin_amdgcn_readfirstlane(__float_as_int(ca.z))) u2 = m32[(size_t)(v + 2) * 64];
    if (__builtin_amdgcn_readfirstlane(__float_as_int(ca.w))) u3 = m32[(size_t)(v + 3) * 64];
    if (__builtin_amdgcn_readfirstlane(__float_as_int(cb.x))) u4 = m32[(size_t)(v + 4) * 64];
    if (__builtin_amdgcn_readfirstlane(__float_as_int(cb.y))) u5 = m32[(size_t)(v + 5) * 64];
    if (__builtin_amdgcn_readfirstlane(__float_as_int(cb.z))) u6 = m32[(size_t)(v + 6) * 64];
    if (__builtin_amdgcn_readfirstlane(__float_as_int(cb.w))) u7 = m32[(size_t)(v + 7) * 64];
    ax = fmaf(ca.x, bfLo(u0), ax); ay = fmaf(ca.x, bfHi(u0), ay);
    ax = fmaf(ca.y, bfLo(u1), ax); ay = fmaf(ca.y, bfHi(u1), ay);
    ax = fmaf(ca.z, bfLo(u2), ax); ay = fmaf(ca.z, bfHi(u2), ay);
    ax = fmaf(ca.w, bfLo(u3), ax); ay = fmaf(ca.w, bfHi(u3), ay);
    ax = fmaf(cb.x, bfLo(u4), ax); ay = fmaf(cb.x, bfHi(u4), ay);
    ax = fmaf(cb.y, bfLo(u5), ax); ay = fmaf(cb.y, bfHi(u5), ay);
    ax = fmaf(cb.z, bfLo(u6), ax); ay = fmaf(cb.z, bfHi(u6), ay);
    ax = fmaf(cb.w, bfLo(u7), ax); ay = fmaf(cb.w, bfHi(u7), ay);
  }
  float* fs = P + g * FEAT + 2 * lane;
  atomicAdd(fs, ax);
  atomicAdd(fs + 1, ay);
}

// ---------------- per-graph node counts (LDS binned) ---------------------
__global__ __launch_bounds__(256) void count_graphs(const int* __restrict__ batch,
                                                    float* __restrict__ cnt_g) {
  __shared__ int bins[NGRAPH];
  if (threadIdx.x < NGRAPH) bins[threadIdx.x] = 0;
  __syncthreads();
  int i = blockIdx.x * 256 + threadIdx.x;
  if (i < N_NODES) atomicAdd(&bins[batch[i]], 1);
  __syncthreads();
  if (threadIdx.x < NGRAPH && bins[threadIdx.x] > 0)
    atomicAdd(&cnt_g[threadIdx.x], (float)bins[threadIdx.x]);
}

// ---------------- Pn = P / cnt  (before the W3 GEMM) ---------------------
__global__ __launch_bounds__(256) void finalize_pre(const float* __restrict__ P,
                                                    const float* __restrict__ cnt_g,
                                                    float* __restrict__ Pn) {
  int i = blockIdx.x * 256 + threadIdx.x;
  if (i < NGRAPH * FEAT) {
    float c = fmaxf(cnt_g[i >> 7], 1.0f);
    Pn[i] = P[i] / c;
  }
}

// ---------------- FC: split-K atomic GEMM --------------------------------
__global__ __launch_bounds__(256) void fc_init(const float* __restrict__ b,
                                               float* __restrict__ out, int C) {
  int i = blockIdx.x * 256 + threadIdx.x;
  if (i < NGRAPH * C) out[i] = b[i % C];
}

__global__ __launch_bounds__(256) void fc_accum(const float* __restrict__ in,
                                                const float* __restrict__ w,
                                                float* __restrict__ out,
                                                int K, int C, int relu_in,
                                                int cstrips, int kchunks) {
  int wave = (blockIdx.x * 256 + threadIdx.x) >> 6;
  int lane = threadIdx.x & 63;
  int perrow = cstrips * kchunks;
  int r = wave / perrow;
  if (r >= NGRAPH) return;
  int rem = wave - r * perrow;
  int cs = rem / kchunks;
  int kc = rem - cs * kchunks;
  int c = cs * 64 + lane;
  if (c >= C) return;
  const float* inr = in + (size_t)r * K + kc * 64;
  const float* wp = w + (size_t)(kc * 64) * C + c;
  float a0 = 0.f, a1 = 0.f, a2 = 0.f, a3 = 0.f;
#pragma unroll 4
  for (int k = 0; k < 64; k += 4) {
    float i0 = inr[k], i1 = inr[k + 1], i2 = inr[k + 2], i3 = inr[k + 3];
    if (relu_in) {
      i0 = fmaxf(i0, 0.f); i1 = fmaxf(i1, 0.f);
      i2 = fmaxf(i2, 0.f); i3 = fmaxf(i3, 0.f);
    }
    a0 = fmaf(i0, wp[(size_t)k * C], a0);
    a1 = fmaf(i1, wp[(size_t)(k + 1) * C], a1);
    a2 = fmaf(i2, wp[(size_t)(k + 2) * C], a2);
    a3 = fmaf(i3, wp[(size_t)(k + 3) * C], a3);
  }
  atomicAdd(&out[(size_t)r * C + c], (a0 + a1) + (a2 + a3));
}

static inline void fc_run(const float* in, const float* w, const float* b,
                          float* out, int K, int C, int relu_in,
                          hipStream_t stream) {
  int cstrips = (C + 63) / 64;
  int kchunks = K / 64;
  fc_init<<<(NGRAPH * C + 255) / 256, 256, 0, stream>>>(b, out, C);
  int waves = NGRAPH * cstrips * kchunks;
  fc_accum<<<(waves * 64 + 255) / 256, 256, 0, stream>>>(in, w, out, K, C,
                                                         relu_in, cstrips, kchunks);
}

// =========================================================================
extern "C" void kernel_launch(void* const* d_in, const int* in_sizes, int n_in,
                              void* d_out, int out_size, void* d_ws, size_t ws_size,
                              hipStream_t stream) {
  const float* x         = (const float*)d_in[0];
  const int*   ei        = (const int*)d_in[1];     // [2][E]: row0 src, row1 dst
  const int*   batch     = (const int*)d_in[2];
  const float* conv_w[3] = {(const float*)d_in[3], (const float*)d_in[5], (const float*)d_in[7]};
  const float* conv_b[3] = {(const float*)d_in[4], (const float*)d_in[6], (const float*)d_in[8]};
  const float* fc_w[5]   = {(const float*)d_in[9],  (const float*)d_in[11],
                            (const float*)d_in[13], (const float*)d_in[15],
                            (const float*)d_in[17]};
  const float* fc_b[5]   = {(const float*)d_in[10], (const float*)d_in[12],
                            (const float*)d_in[14], (const float*)d_in[16],
                            (const float*)d_in[18]};
  const int* e_src = ei;
  const int* e_dst = ei + N_EDGES;
  float* out_f = (float*)d_out;                  // [64][128] fp32  (output 0)
  float* out_y = (float*)d_out + NGRAPH * FEAT;  // [64][10]  fp32  (output 1)

  char* p = (char*)d_ws;
  auto carve = [&](size_t bytes) {
    char* r = p;
    p += (bytes + 255) & ~(size_t)255;
    return r;
  };
  int*    cnt_i   = (int*)carve(N_NODES * 4);
  float*  dinv    = (float*)carve(N_NODES * 4);
  int*    csr_ptr = (int*)carve(N_NODES * 4);
  int*    cursor  = (int*)carve(N_NODES * 4);
  int*    bsums   = (int*)carve(256 * 4);
  int2*   edges   = (int2*)carve((size_t)N_EDGES * 8);
  ushort* xb      = (ushort*)carve((size_t)N_NODES * FEAT * 2);   // bf16 x
  ushort* wb      = (ushort*)carve((size_t)2 * FEAT * FEAT * 2);  // bf16 conv1/2 weights
  ushort* msl     = (ushort*)carve((size_t)N_NODES * FEAT * 2);   // bf16 messages XW
  ushort* hbuf    = (ushort*)carve((size_t)N_NODES * FEAT * 2);   // bf16 h
  float*  coefT   = (float*)carve((size_t)NGRAPH * N_NODES * 4);  // 12.8 MB
  float*  f_sum   = (float*)carve(NGRAPH * FEAT * 4);             // P
  float*  pnorm   = (float*)carve(NGRAPH * FEAT * 4);             // P/cnt
  float*  cnt_g   = (float*)carve(NGRAPH * 4);
  float*  act1    = (float*)carve(NGRAPH * 1024 * 4);
  float*  act2    = (float*)carve(NGRAPH * 512 * 4);
  float*  act3    = (float*)carve(NGRAPH * 256 * 4);
  float*  act4    = (float*)carve(NGRAPH * 128 * 4);

  const int BLK_E = (N_EDGES + 255) / 256;
  const int BLK_N = (N_NODES + 255) / 256;

  hipMemsetAsync(cnt_i, 0, N_NODES * 4, stream);
  hipMemsetAsync(coefT, 0, (size_t)NGRAPH * N_NODES * 4, stream);
  hipMemsetAsync(f_sum, 0, NGRAPH * FEAT * 4, stream);
  hipMemsetAsync(cnt_g, 0, NGRAPH * 4, stream);

  // ---- fp32 -> bf16 prep (x, conv1/2 weights; conv3 stays fp32) ----
  cvt_bf16<<<(N_NODES * FEAT / 4 + 255) / 256, 256, 0, stream>>>(x, xb, N_NODES * FEAT / 4);
  cvt_bf16<<<(FEAT * FEAT / 4 + 255) / 256, 256, 0, stream>>>(conv_w[0], wb,               FEAT * FEAT / 4);
  cvt_bf16<<<(FEAT * FEAT / 4 + 255) / 256, 256, 0, stream>>>(conv_w[1], wb + FEAT * FEAT, FEAT * FEAT / 4);

  // ---- build CSR + norms + coefT ----
  count_deg<<<BLK_E, 256, 0, stream>>>(e_dst, cnt_i);
  compute_dinv<<<BLK_N, 256, 0, stream>>>(cnt_i, batch, dinv, coefT);
  scan1<<<BLK_N, 256, 0, stream>>>(cnt_i, csr_ptr, bsums);
  scan2<<<1, 256, 0, stream>>>(bsums, BLK_N);
  scan3<<<BLK_N, 256, 0, stream>>>(csr_ptr, cursor, bsums);
  fill_csr<<<BLK_E, 256, 0, stream>>>(e_src, e_dst, dinv, batch, cursor, edges, coefT);

  const int GEMM_BLKS = (N_NODES / 16) * 8 / 4;
  const int AGG_BLKS  = (N_NODES + 3) / 4;
  const int POOL_BLKS = (NCHUNKS * NGRAPH) / 4;   // 1568

  // ---- conv1 ----
  gemm128<<<GEMM_BLKS, 256, 0, stream>>>(xb, wb, msl, N_NODES / 16);
  agg_kernel<<<AGG_BLKS, 256, 0, stream>>>(msl, dinv, csr_ptr, cnt_i, edges,
                                           conv_b[0], hbuf);
  // ---- conv2 ----
  gemm128<<<GEMM_BLKS, 256, 0, stream>>>(hbuf, wb + FEAT * FEAT, msl, N_NODES / 16);
  agg_kernel<<<AGG_BLKS, 256, 0, stream>>>(msl, dinv, csr_ptr, cnt_i, edges,
                                           conv_b[1], hbuf);
  // ---- conv3 (algebraic): pool h2 first, then tiny GEMM with W3 ----
  pool_gemm<<<POOL_BLKS, 256, 0, stream>>>(hbuf, coefT, f_sum);
  count_graphs<<<BLK_N, 256, 0, stream>>>(batch, cnt_g);
  finalize_pre<<<(NGRAPH * FEAT + 255) / 256, 256, 0, stream>>>(f_sum, cnt_g, pnorm);
  fc_run(pnorm, conv_w[2], conv_b[2], out_f, 128, 128, 0, stream);  // f = Pn*W3 + b3

  // ---- FC head: split-K atomic GEMMs, relu fused into next layer's read ----
  fc_run(out_f, fc_w[0], fc_b[0], act1, 128, 1024, 0, stream);
  fc_run(act1,  fc_w[1], fc_b[1], act2, 1024, 512, 1, stream);
  fc_run(act2,  fc_w[2], fc_b[2], act3, 512, 256, 1, stream);
  fc_run(act3,  fc_w[3], fc_b[3], act4, 256, 128, 1, stream);
  fc_run(act4,  fc_w[4], fc_b[4], out_y, 128, 10, 1, stream);
}

// Round 11
// 499.213 us; speedup vs baseline: 1.8408x; 1.0005x over previous
//
#include <hip/hip_runtime.h>
#include <stdint.h>

#define N_NODES 50000
#define N_EDGES 800000
#define FEAT    128
#define NGRAPH  64
#define PCHUNK  512      // pool_gemm nodes per wave-chunk
#define NCHUNKS ((N_NODES + PCHUNK - 1) / PCHUNK)   // 98

typedef __attribute__((ext_vector_type(8))) short short8;
typedef __attribute__((ext_vector_type(4))) float floatx4;

static __device__ __forceinline__ ushort f2bf(float f) {
  uint32_t x = __float_as_uint(f);
  x += 0x7FFF + ((x >> 16) & 1);   // RNE
  return (ushort)(x >> 16);
}
static __device__ __forceinline__ float bfLo(uint32_t u) {
  return __uint_as_float(u << 16);
}
static __device__ __forceinline__ float bfHi(uint32_t u) {
  return __uint_as_float(u & 0xFFFF0000u);
}

// ---------------- fp32 -> bf16 row-major ---------------------------------
__global__ __launch_bounds__(256) void cvt_bf16(const float* __restrict__ in,
                                                ushort* __restrict__ out, int n4) {
  int i = blockIdx.x * 256 + threadIdx.x;
  if (i >= n4) return;
  float4 v = ((const float4*)in)[i];
  ushort4 u;
  u.x = f2bf(v.x); u.y = f2bf(v.y); u.z = f2bf(v.z); u.w = f2bf(v.w);
  ((ushort4*)out)[i] = u;
}

// ---------------- degree count -------------------------------------------
__global__ __launch_bounds__(256) void count_deg(const int* __restrict__ dst,
                                                 int* __restrict__ cnt) {
  int e = blockIdx.x * 256 + threadIdx.x;
  if (e < N_EDGES) atomicAdd(&cnt[dst[e]], 1);
}

// dinv + coef self-term + per-graph node counts (LDS binned)
__global__ __launch_bounds__(256) void compute_dinv(const int* __restrict__ cnt,
                                                    const int* __restrict__ batch,
                                                    float* __restrict__ dinv,
                                                    float* __restrict__ coefT,
                                                    float* __restrict__ cnt_g) {
  __shared__ int bins[NGRAPH];
  if (threadIdx.x < NGRAPH) bins[threadIdx.x] = 0;
  __syncthreads();
  int i = blockIdx.x * 256 + threadIdx.x;
  if (i < N_NODES) {
    float di = rsqrtf((float)cnt[i] + 1.0f);
    dinv[i] = di;
    int g = batch[i];
    coefT[(size_t)g * N_NODES + i] = di * di;   // coalesced (batch sorted)
    atomicAdd(&bins[g], 1);
  }
  __syncthreads();
  if (threadIdx.x < NGRAPH && bins[threadIdx.x] > 0)
    atomicAdd(&cnt_g[threadIdx.x], (float)bins[threadIdx.x]);
}

// ---------------- exclusive scan (3 kernels) -----------------------------
__global__ __launch_bounds__(256) void scan1(const int* __restrict__ cnt,
                                             int* __restrict__ ptr,
                                             int* __restrict__ bsums) {
  __shared__ int tmp[256];
  int i = blockIdx.x * 256 + threadIdx.x;
  int v = (i < N_NODES) ? cnt[i] : 0;
  tmp[threadIdx.x] = v;
  __syncthreads();
  for (int off = 1; off < 256; off <<= 1) {
    int t = (threadIdx.x >= off) ? tmp[threadIdx.x - off] : 0;
    __syncthreads();
    tmp[threadIdx.x] += t;
    __syncthreads();
  }
  if (i < N_NODES) ptr[i] = tmp[threadIdx.x] - v;           // exclusive
  if (threadIdx.x == 255) bsums[blockIdx.x] = tmp[255];
}

__global__ __launch_bounds__(256) void scan2(int* __restrict__ bsums, int nb) {
  __shared__ int tmp[256];
  int v = (threadIdx.x < nb) ? bsums[threadIdx.x] : 0;
  tmp[threadIdx.x] = v;
  __syncthreads();
  for (int off = 1; off < 256; off <<= 1) {
    int t = (threadIdx.x >= off) ? tmp[threadIdx.x - off] : 0;
    __syncthreads();
    tmp[threadIdx.x] += t;
    __syncthreads();
  }
  if (threadIdx.x < nb) bsums[threadIdx.x] = tmp[threadIdx.x] - v;  // exclusive
}

__global__ __launch_bounds__(256) void scan3(int* __restrict__ ptr,
                                             int* __restrict__ cursor,
                                             const int* __restrict__ bsums) {
  int i = blockIdx.x * 256 + threadIdx.x;
  if (i < N_NODES) {
    int p = ptr[i] + bsums[blockIdx.x];
    ptr[i] = p;
    cursor[i] = p;
  }
}

// ---------------- CSR fill: src+norm, plus graph-id per position ---------
__global__ __launch_bounds__(256) void fill_csr(const int* __restrict__ src,
                                                const int* __restrict__ dst,
                                                const float* __restrict__ dinv,
                                                const int* __restrict__ batch,
                                                int* __restrict__ cursor,
                                                int2* __restrict__ edges,
                                                int* __restrict__ ebg) {
  int e = blockIdx.x * 256 + threadIdx.x;
  if (e >= N_EDGES) return;
  int s = src[e], d = dst[e];
  int pos = atomicAdd(&cursor[d], 1);
  float nrm = dinv[s] * dinv[d];
  edges[pos] = make_int2(s, __float_as_int(nrm));
  ebg[pos] = batch[d];          // batch is L2-hot (200 KB)
}

// ---------------- coef edge terms from dst-sorted CSR positions ----------
// Consecutive positions share graph g -> atomics localized to one 200 KB
// coef row (L2-resident), unlike the original-edge-order scatter.
__global__ __launch_bounds__(256) void coef_build(const int2* __restrict__ edges,
                                                  const int* __restrict__ ebg,
                                                  float* __restrict__ coefT) {
  int i = blockIdx.x * 256 + threadIdx.x;
  if (i >= N_EDGES) return;
  int2 e = edges[i];
  int g = ebg[i];
  atomicAdd(&coefT[(size_t)g * N_NODES + e.x], __int_as_float(e.y));
}

// ---------------- GEMM [M,128] x [128,128] via MFMA bf16, bf16 out -------
__global__ __launch_bounds__(256) void gemm128(const ushort* __restrict__ X,
                                               const ushort* __restrict__ W,
                                               ushort* __restrict__ XW,
                                               int nTilesM) {
  int wave = (blockIdx.x * 256 + threadIdx.x) >> 6;
  int lane = threadIdx.x & 63;
  int mt = wave >> 3;  // 8 n-tiles per m-tile
  int nt = wave & 7;
  if (mt >= nTilesM) return;
  int m0 = mt * 16, n0 = nt * 16;
  int r = lane & 15, quad = lane >> 4;
  floatx4 acc = {0.f, 0.f, 0.f, 0.f};
  const ushort* xrow = X + (size_t)(m0 + r) * FEAT;
#pragma unroll
  for (int kb = 0; kb < 4; ++kb) {
    int k0 = kb * 32 + quad * 8;
    short8 a = *(const short8*)(xrow + k0);
    short8 b;
#pragma unroll
    for (int j = 0; j < 8; ++j) b[j] = (short)W[(size_t)(k0 + j) * FEAT + n0 + r];
    acc = __builtin_amdgcn_mfma_f32_16x16x32_bf16(a, b, acc, 0, 0, 0);
  }
#pragma unroll
  for (int reg = 0; reg < 4; ++reg) {
    int row = quad * 4 + reg;
    XW[(size_t)(m0 + row) * FEAT + n0 + r] = f2bf(acc[reg]);
  }
}

// ---------------- aggregation (r6 proven): wave/node, 8-edge ILP ---------
__global__ __launch_bounds__(256) void agg_kernel(const ushort* __restrict__ msg,
                                                  const float* __restrict__ dinv,
                                                  const int* __restrict__ ptr,
                                                  const int* __restrict__ cnt,
                                                  const int2* __restrict__ edges,
                                                  const float* __restrict__ bias,
                                                  ushort* __restrict__ Hout) {
  int wave = (blockIdx.x * 256 + threadIdx.x) >> 6;
  int lane = threadIdx.x & 63;
  if (wave >= N_NODES) return;
  int v = wave;
  float di = dinv[v];
  const uint32_t* m32 = (const uint32_t*)msg;   // 64 dwords per node row
  uint32_t su = m32[(size_t)v * 64 + lane];
  float sn = di * di;
  float ax0 = bfLo(su) * sn, ay0 = bfHi(su) * sn;
  float ax1 = 0.f, ay1 = 0.f, ax2 = 0.f, ay2 = 0.f, ax3 = 0.f, ay3 = 0.f;
  int start = ptr[v];
  int n = cnt[v];
  int i = 0;
  if ((start & 1) && n > 0) {
    int2 e = edges[start];
    uint32_t u = m32[(size_t)e.x * 64 + lane];
    float nrm = __int_as_float(e.y);
    ax0 = fmaf(nrm, bfLo(u), ax0);
    ay0 = fmaf(nrm, bfHi(u), ay0);
    i = 1;
  }
  for (; i + 8 <= n; i += 8) {
    const int4* ep = (const int4*)(edges + start + i);   // 16B-aligned
    int4 q0 = ep[0], q1 = ep[1], q2 = ep[2], q3 = ep[3];
    uint32_t u0 = m32[(size_t)q0.x * 64 + lane];
    uint32_t u1 = m32[(size_t)q0.z * 64 + lane];
    uint32_t u2 = m32[(size_t)q1.x * 64 + lane];
    uint32_t u3 = m32[(size_t)q1.z * 64 + lane];
    uint32_t u4 = m32[(size_t)q2.x * 64 + lane];
    uint32_t u5 = m32[(size_t)q2.z * 64 + lane];
    uint32_t u6 = m32[(size_t)q3.x * 64 + lane];
    uint32_t u7 = m32[(size_t)q3.z * 64 + lane];
    float n0 = __int_as_float(q0.y), n1 = __int_as_float(q0.w);
    float n2 = __int_as_float(q1.y), n3 = __int_as_float(q1.w);
    float n4 = __int_as_float(q2.y), n5 = __int_as_float(q2.w);
    float n6 = __int_as_float(q3.y), n7 = __int_as_float(q3.w);
    ax0 = fmaf(n0, bfLo(u0), ax0); ay0 = fmaf(n0, bfHi(u0), ay0);
    ax1 = fmaf(n1, bfLo(u1), ax1); ay1 = fmaf(n1, bfHi(u1), ay1);
    ax2 = fmaf(n2, bfLo(u2), ax2); ay2 = fmaf(n2, bfHi(u2), ay2);
    ax3 = fmaf(n3, bfLo(u3), ax3); ay3 = fmaf(n3, bfHi(u3), ay3);
    ax0 = fmaf(n4, bfLo(u4), ax0); ay0 = fmaf(n4, bfHi(u4), ay0);
    ax1 = fmaf(n5, bfLo(u5), ax1); ay1 = fmaf(n5, bfHi(u5), ay1);
    ax2 = fmaf(n6, bfLo(u6), ax2); ay2 = fmaf(n6, bfHi(u6), ay2);
    ax3 = fmaf(n7, bfLo(u7), ax3); ay3 = fmaf(n7, bfHi(u7), ay3);
  }
  for (; i < n; ++i) {
    int2 e = edges[start + i];
    float nrm = __int_as_float(e.y);
    uint32_t u = m32[(size_t)e.x * 64 + lane];
    ax0 = fmaf(nrm, bfLo(u), ax0);
    ay0 = fmaf(nrm, bfHi(u), ay0);
  }
  float ax = (ax0 + ax1) + (ax2 + ax3) + bias[2 * lane];
  float ay = (ay0 + ay1) + (ay2 + ay3) + bias[2 * lane + 1];
  ax = fmaxf(ax, 0.f);
  ay = fmaxf(ay, 0.f);
  ushort2 h2;
  h2.x = f2bf(ax);
  h2.y = f2bf(ay);
  ((ushort2*)Hout)[(size_t)v * 64 + lane] = h2;
}

// ---------------- pool v3: P = coefT x h2, 8-wide predicated ILP ---------
__global__ __launch_bounds__(256) void pool_gemm(const ushort* __restrict__ h2,
                                                 const float* __restrict__ coefT,
                                                 float* __restrict__ P) {
  int w = (blockIdx.x * 256 + threadIdx.x) >> 6;
  int lane = threadIdx.x & 63;
  int g = w & 63;
  int ck = w >> 6;
  if (ck >= NCHUNKS) return;
  int c0 = ck * PCHUNK;
  int nv = min(PCHUNK, N_NODES - c0);            // 512, last chunk 336 (8|336)
  const float* crow = coefT + (size_t)g * N_NODES + c0;
  const uint32_t* m32 = (const uint32_t*)h2 + (size_t)c0 * 64 + lane;
  float ax = 0.f, ay = 0.f;
  for (int v = 0; v + 8 <= nv; v += 8) {
    float4 ca = *(const float4*)(crow + v);
    float4 cb = *(const float4*)(crow + v + 4);
    uint32_t u0 = 0, u1 = 0, u2 = 0, u3 = 0, u4 = 0, u5 = 0, u6 = 0, u7 = 0;
    if (__builtin_amdgcn_readfirstlane(__float_as_int(ca.x))) u0 = m32[(size_t)(v + 0) * 64];
    if (__builtin_amdgcn_readfirstlane(__float_as_int(ca.y))) u1 = m32[(size_t)(v + 1) * 64];
    if (__builtin_amdgcn_readfirstlane(__float_as_int(ca.z))) u2 = m32[(size_t)(v + 2) * 64];
    if (__builtin_amdgcn_readfirstlane(__float_as_int(ca.w))) u3 = m32[(size_t)(v + 3) * 64];
    if (__builtin_amdgcn_readfirstlane(__float_as_int(cb.x))) u4 = m32[(size_t)(v + 4) * 64];
    if (__builtin_amdgcn_readfirstlane(__float_as_int(cb.y))) u5 = m32[(size_t)(v + 5) * 64];
    if (__builtin_amdgcn_readfirstlane(__float_as_int(cb.z))) u6 = m32[(size_t)(v + 6) * 64];
    if (__builtin_amdgcn_readfirstlane(__float_as_int(cb.w))) u7 = m32[(size_t)(v + 7) * 64];
    ax = fmaf(ca.x, bfLo(u0), ax); ay = fmaf(ca.x, bfHi(u0), ay);
    ax = fmaf(ca.y, bfLo(u1), ax); ay = fmaf(ca.y, bfHi(u1), ay);
    ax = fmaf(ca.z, bfLo(u2), ax); ay = fmaf(ca.z, bfHi(u2), ay);
    ax = fmaf(ca.w, bfLo(u3), ax); ay = fmaf(ca.w, bfHi(u3), ay);
    ax = fmaf(cb.x, bfLo(u4), ax); ay = fmaf(cb.x, bfHi(u4), ay);
    ax = fmaf(cb.y, bfLo(u5), ax); ay = fmaf(cb.y, bfHi(u5), ay);
    ax = fmaf(cb.z, bfLo(u6), ax); ay = fmaf(cb.z, bfHi(u6), ay);
    ax = fmaf(cb.w, bfLo(u7), ax); ay = fmaf(cb.w, bfHi(u7), ay);
  }
  float* fs = P + g * FEAT + 2 * lane;
  atomicAdd(fs, ax);
  atomicAdd(fs + 1, ay);
}

// ---------------- Pn = P / cnt  (before the W3 GEMM) ---------------------
__global__ __launch_bounds__(256) void finalize_pre(const float* __restrict__ P,
                                                    const float* __restrict__ cnt_g,
                                                    float* __restrict__ Pn) {
  int i = blockIdx.x * 256 + threadIdx.x;
  if (i < NGRAPH * FEAT) {
    float c = fmaxf(cnt_g[i >> 7], 1.0f);
    Pn[i] = P[i] / c;
  }
}

// ---------------- FC: split-K atomic GEMM, bias folded into kc==0 --------
__global__ __launch_bounds__(256) void fc_accum(const float* __restrict__ in,
                                                const float* __restrict__ w,
                                                const float* __restrict__ b,
                                                float* __restrict__ out,
                                                int K, int C, int relu_in,
                                                int cstrips, int kchunks) {
  int wave = (blockIdx.x * 256 + threadIdx.x) >> 6;
  int lane = threadIdx.x & 63;
  int perrow = cstrips * kchunks;
  int r = wave / perrow;
  if (r >= NGRAPH) return;
  int rem = wave - r * perrow;
  int cs = rem / kchunks;
  int kc = rem - cs * kchunks;
  int c = cs * 64 + lane;
  if (c >= C) return;
  const float* inr = in + (size_t)r * K + kc * 64;
  const float* wp = w + (size_t)(kc * 64) * C + c;
  float a0 = (kc == 0) ? b[c] : 0.f;
  float a1 = 0.f, a2 = 0.f, a3 = 0.f;
#pragma unroll 4
  for (int k = 0; k < 64; k += 4) {
    float i0 = inr[k], i1 = inr[k + 1], i2 = inr[k + 2], i3 = inr[k + 3];
    if (relu_in) {
      i0 = fmaxf(i0, 0.f); i1 = fmaxf(i1, 0.f);
      i2 = fmaxf(i2, 0.f); i3 = fmaxf(i3, 0.f);
    }
    a0 = fmaf(i0, wp[(size_t)k * C], a0);
    a1 = fmaf(i1, wp[(size_t)(k + 1) * C], a1);
    a2 = fmaf(i2, wp[(size_t)(k + 2) * C], a2);
    a3 = fmaf(i3, wp[(size_t)(k + 3) * C], a3);
  }
  atomicAdd(&out[(size_t)r * C + c], (a0 + a1) + (a2 + a3));
}

static inline void fc_run(const float* in, const float* w, const float* b,
                          float* out, int K, int C, int relu_in,
                          hipStream_t stream) {
  int cstrips = (C + 63) / 64;
  int kchunks = K / 64;
  int waves = NGRAPH * cstrips * kchunks;
  fc_accum<<<(waves * 64 + 255) / 256, 256, 0, stream>>>(in, w, b, out, K, C,
                                                         relu_in, cstrips, kchunks);
}

// =========================================================================
extern "C" void kernel_launch(void* const* d_in, const int* in_sizes, int n_in,
                              void* d_out, int out_size, void* d_ws, size_t ws_size,
                              hipStream_t stream) {
  const float* x         = (const float*)d_in[0];
  const int*   ei        = (const int*)d_in[1];     // [2][E]: row0 src, row1 dst
  const int*   batch     = (const int*)d_in[2];
  const float* conv_w[3] = {(const float*)d_in[3], (const float*)d_in[5], (const float*)d_in[7]};
  const float* conv_b[3] = {(const float*)d_in[4], (const float*)d_in[6], (const float*)d_in[8]};
  const float* fc_w[5]   = {(const float*)d_in[9],  (const float*)d_in[11],
                            (const float*)d_in[13], (const float*)d_in[15],
                            (const float*)d_in[17]};
  const float* fc_b[5]   = {(const float*)d_in[10], (const float*)d_in[12],
                            (const float*)d_in[14], (const float*)d_in[16],
                            (const float*)d_in[18]};
  const int* e_src = ei;
  const int* e_dst = ei + N_EDGES;
  float* out_f = (float*)d_out;                  // [64][128] fp32  (output 0)
  float* out_y = (float*)d_out + NGRAPH * FEAT;  // [64][10]  fp32  (output 1)

  char* p = (char*)d_ws;
  auto carve = [&](size_t bytes) {
    char* r = p;
    p += (bytes + 255) & ~(size_t)255;
    return r;
  };
  int*    cnt_i   = (int*)carve(N_NODES * 4);
  float*  dinv    = (float*)carve(N_NODES * 4);
  int*    csr_ptr = (int*)carve(N_NODES * 4);
  int*    cursor  = (int*)carve(N_NODES * 4);
  int*    bsums   = (int*)carve(256 * 4);
  int2*   edges   = (int2*)carve((size_t)N_EDGES * 8);
  int*    ebg     = (int*)carve((size_t)N_EDGES * 4);             // graph per CSR pos
  ushort* xb      = (ushort*)carve((size_t)N_NODES * FEAT * 2);   // bf16 x
  ushort* wb      = (ushort*)carve((size_t)2 * FEAT * FEAT * 2);  // bf16 conv1/2 W
  ushort* msl     = (ushort*)carve((size_t)N_NODES * FEAT * 2);   // bf16 messages
  ushort* hbuf    = (ushort*)carve((size_t)N_NODES * FEAT * 2);   // bf16 h
  float*  coefT   = (float*)carve((size_t)NGRAPH * N_NODES * 4);  // 12.8 MB
  float*  f_sum   = (float*)carve(NGRAPH * FEAT * 4);             // P
  float*  cnt_g   = (float*)carve(NGRAPH * 4);                    // adjacent to f_sum
  float*  pnorm   = (float*)carve(NGRAPH * FEAT * 4);             // P/cnt
  float*  act1    = (float*)carve(NGRAPH * 1024 * 4);             // contiguous act block
  float*  act2    = (float*)carve(NGRAPH * 512 * 4);
  float*  act3    = (float*)carve(NGRAPH * 256 * 4);
  float*  act4    = (float*)carve(NGRAPH * 128 * 4);

  const int BLK_E = (N_EDGES + 255) / 256;
  const int BLK_N = (N_NODES + 255) / 256;

  // zero-init (ws + out are poisoned 0xAA each timed call)
  hipMemsetAsync(cnt_i, 0, N_NODES * 4, stream);
  hipMemsetAsync(coefT, 0, (size_t)NGRAPH * N_NODES * 4, stream);
  hipMemsetAsync(f_sum, 0, NGRAPH * FEAT * 4 + 256, stream);        // f_sum + cnt_g
  hipMemsetAsync(act1, 0, (size_t)NGRAPH * (1024 + 512 + 256 + 128) * 4 + 3 * 256, stream);
  hipMemsetAsync(d_out, 0, (size_t)out_size * 4, stream);           // fc targets

  // ---- fp32 -> bf16 prep (x, conv1/2 weights; conv3 stays fp32) ----
  cvt_bf16<<<(N_NODES * FEAT / 4 + 255) / 256, 256, 0, stream>>>(x, xb, N_NODES * FEAT / 4);
  cvt_bf16<<<(FEAT * FEAT / 4 + 255) / 256, 256, 0, stream>>>(conv_w[0], wb,               FEAT * FEAT / 4);
  cvt_bf16<<<(FEAT * FEAT / 4 + 255) / 256, 256, 0, stream>>>(conv_w[1], wb + FEAT * FEAT, FEAT * FEAT / 4);

  // ---- build CSR + norms + coefT ----
  count_deg<<<BLK_E, 256, 0, stream>>>(e_dst, cnt_i);
  compute_dinv<<<BLK_N, 256, 0, stream>>>(cnt_i, batch, dinv, coefT, cnt_g);
  scan1<<<BLK_N, 256, 0, stream>>>(cnt_i, csr_ptr, bsums);
  scan2<<<1, 256, 0, stream>>>(bsums, BLK_N);
  scan3<<<BLK_N, 256, 0, stream>>>(csr_ptr, cursor, bsums);
  fill_csr<<<BLK_E, 256, 0, stream>>>(e_src, e_dst, dinv, batch, cursor, edges, ebg);
  coef_build<<<BLK_E, 256, 0, stream>>>(edges, ebg, coefT);

  const int GEMM_BLKS = (N_NODES / 16) * 8 / 4;
  const int AGG_BLKS  = (N_NODES + 3) / 4;
  const int POOL_BLKS = (NCHUNKS * NGRAPH) / 4;   // 1568

  // ---- conv1 ----
  gemm128<<<GEMM_BLKS, 256, 0, stream>>>(xb, wb, msl, N_NODES / 16);
  agg_kernel<<<AGG_BLKS, 256, 0, stream>>>(msl, dinv, csr_ptr, cnt_i, edges,
                                           conv_b[0], hbuf);
  // ---- conv2 ----
  gemm128<<<GEMM_BLKS, 256, 0, stream>>>(hbuf, wb + FEAT * FEAT, msl, N_NODES / 16);
  agg_kernel<<<AGG_BLKS, 256, 0, stream>>>(msl, dinv, csr_ptr, cnt_i, edges,
                                           conv_b[1], hbuf);
  // ---- conv3 (algebraic): pool h2 first, then tiny GEMM with W3 ----
  pool_gemm<<<POOL_BLKS, 256, 0, stream>>>(hbuf, coefT, f_sum);
  finalize_pre<<<(NGRAPH * FEAT + 255) / 256, 256, 0, stream>>>(f_sum, cnt_g, pnorm);
  fc_run(pnorm, conv_w[2], conv_b[2], out_f, 128, 128, 0, stream);  // f = Pn*W3 + b3

  // ---- FC head: split-K atomic GEMMs, relu fused into next layer's read ----
  fc_run(out_f, fc_w[0], fc_b[0], act1, 128, 1024, 0, stream);
  fc_run(act1,  fc_w[1], fc_b[1], act2, 1024, 512, 1, stream);
  fc_run(act2,  fc_w[2], fc_b[2], act3, 512, 256, 1, stream);
  fc_run(act3,  fc_w[3], fc_b[3], act4, 256, 128, 1, stream);
  fc_run(act4,  fc_w[4], fc_b[4], out_y, 128, 10, 1, stream);
}

// Round 12
// 447.084 us; speedup vs baseline: 2.0554x; 1.1166x over previous
//
#include <hip/hip_runtime.h>
#include <stdint.h>

#define N_NODES 50000
#define N_EDGES 800000
#define N_PAD   50176    // 98 * 512, K-padding for MFMA pool
#define FEAT    128
#define NGRAPH  64
#define PCHUNK  512
#define NCHUNKS (N_PAD / PCHUNK)   // 98

typedef __attribute__((ext_vector_type(8))) short short8;
typedef __attribute__((ext_vector_type(4))) float floatx4;

static __device__ __forceinline__ ushort f2bf(float f) {
  uint32_t x = __float_as_uint(f);
  x += 0x7FFF + ((x >> 16) & 1);   // RNE
  return (ushort)(x >> 16);
}
static __device__ __forceinline__ float bfLo(uint32_t u) {
  return __uint_as_float(u << 16);
}
static __device__ __forceinline__ float bfHi(uint32_t u) {
  return __uint_as_float(u & 0xFFFF0000u);
}

// ---------------- fp32 -> bf16 row-major ---------------------------------
__global__ __launch_bounds__(256) void cvt_bf16(const float* __restrict__ in,
                                                ushort* __restrict__ out, int n4) {
  int i = blockIdx.x * 256 + threadIdx.x;
  if (i >= n4) return;
  float4 v = ((const float4*)in)[i];
  ushort4 u;
  u.x = f2bf(v.x); u.y = f2bf(v.y); u.z = f2bf(v.z); u.w = f2bf(v.w);
  ((ushort4*)out)[i] = u;
}

// ---------------- degree count -------------------------------------------
__global__ __launch_bounds__(256) void count_deg(const int* __restrict__ dst,
                                                 int* __restrict__ cnt) {
  int e = blockIdx.x * 256 + threadIdx.x;
  if (e < N_EDGES) atomicAdd(&cnt[dst[e]], 1);
}

// dinv + coef self-term + per-graph node counts (LDS binned)
__global__ __launch_bounds__(256) void compute_dinv(const int* __restrict__ cnt,
                                                    const int* __restrict__ batch,
                                                    float* __restrict__ dinv,
                                                    float* __restrict__ coefT,
                                                    float* __restrict__ cnt_g) {
  __shared__ int bins[NGRAPH];
  if (threadIdx.x < NGRAPH) bins[threadIdx.x] = 0;
  __syncthreads();
  int i = blockIdx.x * 256 + threadIdx.x;
  if (i < N_NODES) {
    float di = rsqrtf((float)cnt[i] + 1.0f);
    dinv[i] = di;
    int g = batch[i];
    coefT[(size_t)g * N_PAD + i] = di * di;   // coalesced (batch sorted)
    atomicAdd(&bins[g], 1);
  }
  __syncthreads();
  if (threadIdx.x < NGRAPH && bins[threadIdx.x] > 0)
    atomicAdd(&cnt_g[threadIdx.x], (float)bins[threadIdx.x]);
}

// ---------------- exclusive scan (3 kernels) -----------------------------
__global__ __launch_bounds__(256) void scan1(const int* __restrict__ cnt,
                                             int* __restrict__ ptr,
                                             int* __restrict__ bsums) {
  __shared__ int tmp[256];
  int i = blockIdx.x * 256 + threadIdx.x;
  int v = (i < N_NODES) ? cnt[i] : 0;
  tmp[threadIdx.x] = v;
  __syncthreads();
  for (int off = 1; off < 256; off <<= 1) {
    int t = (threadIdx.x >= off) ? tmp[threadIdx.x - off] : 0;
    __syncthreads();
    tmp[threadIdx.x] += t;
    __syncthreads();
  }
  if (i < N_NODES) ptr[i] = tmp[threadIdx.x] - v;           // exclusive
  if (threadIdx.x == 255) bsums[blockIdx.x] = tmp[255];
}

__global__ __launch_bounds__(256) void scan2(int* __restrict__ bsums, int nb) {
  __shared__ int tmp[256];
  int v = (threadIdx.x < nb) ? bsums[threadIdx.x] : 0;
  tmp[threadIdx.x] = v;
  __syncthreads();
  for (int off = 1; off < 256; off <<= 1) {
    int t = (threadIdx.x >= off) ? tmp[threadIdx.x - off] : 0;
    __syncthreads();
    tmp[threadIdx.x] += t;
    __syncthreads();
  }
  if (threadIdx.x < nb) bsums[threadIdx.x] = tmp[threadIdx.x] - v;  // exclusive
}

__global__ __launch_bounds__(256) void scan3(int* __restrict__ ptr,
                                             int* __restrict__ cursor,
                                             const int* __restrict__ bsums) {
  int i = blockIdx.x * 256 + threadIdx.x;
  if (i < N_NODES) {
    int p = ptr[i] + bsums[blockIdx.x];
    ptr[i] = p;
    cursor[i] = p;
  }
}

// ---------------- CSR fill: src+norm, plus graph-id per position ---------
__global__ __launch_bounds__(256) void fill_csr(const int* __restrict__ src,
                                                const int* __restrict__ dst,
                                                const float* __restrict__ dinv,
                                                const int* __restrict__ batch,
                                                int* __restrict__ cursor,
                                                int2* __restrict__ edges,
                                                int* __restrict__ ebg) {
  int e = blockIdx.x * 256 + threadIdx.x;
  if (e >= N_EDGES) return;
  int s = src[e], d = dst[e];
  int pos = atomicAdd(&cursor[d], 1);
  float nrm = dinv[s] * dinv[d];
  edges[pos] = make_int2(s, __float_as_int(nrm));
  ebg[pos] = batch[d];          // batch is L2-hot (200 KB)
}

// ---------------- coef edge terms from dst-sorted CSR positions ----------
__global__ __launch_bounds__(256) void coef_build(const int2* __restrict__ edges,
                                                  const int* __restrict__ ebg,
                                                  float* __restrict__ coefT) {
  int i = blockIdx.x * 256 + threadIdx.x;
  if (i >= N_EDGES) return;
  int2 e = edges[i];
  int g = ebg[i];
  atomicAdd(&coefT[(size_t)g * N_PAD + e.x], __int_as_float(e.y));
}

// ---------------- GEMM [M,128] x [128,128] via MFMA bf16, bf16 out -------
__global__ __launch_bounds__(256) void gemm128(const ushort* __restrict__ X,
                                               const ushort* __restrict__ W,
                                               ushort* __restrict__ XW,
                                               int nTilesM) {
  int wave = (blockIdx.x * 256 + threadIdx.x) >> 6;
  int lane = threadIdx.x & 63;
  int mt = wave >> 3;  // 8 n-tiles per m-tile
  int nt = wave & 7;
  if (mt >= nTilesM) return;
  int m0 = mt * 16, n0 = nt * 16;
  int r = lane & 15, quad = lane >> 4;
  floatx4 acc = {0.f, 0.f, 0.f, 0.f};
  const ushort* xrow = X + (size_t)(m0 + r) * FEAT;
#pragma unroll
  for (int kb = 0; kb < 4; ++kb) {
    int k0 = kb * 32 + quad * 8;
    short8 a = *(const short8*)(xrow + k0);
    short8 b;
#pragma unroll
    for (int j = 0; j < 8; ++j) b[j] = (short)W[(size_t)(k0 + j) * FEAT + n0 + r];
    acc = __builtin_amdgcn_mfma_f32_16x16x32_bf16(a, b, acc, 0, 0, 0);
  }
#pragma unroll
  for (int reg = 0; reg < 4; ++reg) {
    int row = quad * 4 + reg;
    XW[(size_t)(m0 + row) * FEAT + n0 + r] = f2bf(acc[reg]);
  }
}

// ---------------- aggregation (r6 proven): wave/node, 8-edge ILP ---------
__global__ __launch_bounds__(256) void agg_kernel(const ushort* __restrict__ msg,
                                                  const float* __restrict__ dinv,
                                                  const int* __restrict__ ptr,
                                                  const int* __restrict__ cnt,
                                                  const int2* __restrict__ edges,
                                                  const float* __restrict__ bias,
                                                  ushort* __restrict__ Hout) {
  int wave = (blockIdx.x * 256 + threadIdx.x) >> 6;
  int lane = threadIdx.x & 63;
  if (wave >= N_NODES) return;
  int v = wave;
  float di = dinv[v];
  const uint32_t* m32 = (const uint32_t*)msg;   // 64 dwords per node row
  uint32_t su = m32[(size_t)v * 64 + lane];
  float sn = di * di;
  float ax0 = bfLo(su) * sn, ay0 = bfHi(su) * sn;
  float ax1 = 0.f, ay1 = 0.f, ax2 = 0.f, ay2 = 0.f, ax3 = 0.f, ay3 = 0.f;
  int start = ptr[v];
  int n = cnt[v];
  int i = 0;
  if ((start & 1) && n > 0) {
    int2 e = edges[start];
    uint32_t u = m32[(size_t)e.x * 64 + lane];
    float nrm = __int_as_float(e.y);
    ax0 = fmaf(nrm, bfLo(u), ax0);
    ay0 = fmaf(nrm, bfHi(u), ay0);
    i = 1;
  }
  for (; i + 8 <= n; i += 8) {
    const int4* ep = (const int4*)(edges + start + i);   // 16B-aligned
    int4 q0 = ep[0], q1 = ep[1], q2 = ep[2], q3 = ep[3];
    uint32_t u0 = m32[(size_t)q0.x * 64 + lane];
    uint32_t u1 = m32[(size_t)q0.z * 64 + lane];
    uint32_t u2 = m32[(size_t)q1.x * 64 + lane];
    uint32_t u3 = m32[(size_t)q1.z * 64 + lane];
    uint32_t u4 = m32[(size_t)q2.x * 64 + lane];
    uint32_t u5 = m32[(size_t)q2.z * 64 + lane];
    uint32_t u6 = m32[(size_t)q3.x * 64 + lane];
    uint32_t u7 = m32[(size_t)q3.z * 64 + lane];
    float n0 = __int_as_float(q0.y), n1 = __int_as_float(q0.w);
    float n2 = __int_as_float(q1.y), n3 = __int_as_float(q1.w);
    float n4 = __int_as_float(q2.y), n5 = __int_as_float(q2.w);
    float n6 = __int_as_float(q3.y), n7 = __int_as_float(q3.w);
    ax0 = fmaf(n0, bfLo(u0), ax0); ay0 = fmaf(n0, bfHi(u0), ay0);
    ax1 = fmaf(n1, bfLo(u1), ax1); ay1 = fmaf(n1, bfHi(u1), ay1);
    ax2 = fmaf(n2, bfLo(u2), ax2); ay2 = fmaf(n2, bfHi(u2), ay2);
    ax3 = fmaf(n3, bfLo(u3), ax3); ay3 = fmaf(n3, bfHi(u3), ay3);
    ax0 = fmaf(n4, bfLo(u4), ax0); ay0 = fmaf(n4, bfHi(u4), ay0);
    ax1 = fmaf(n5, bfLo(u5), ax1); ay1 = fmaf(n5, bfHi(u5), ay1);
    ax2 = fmaf(n6, bfLo(u6), ax2); ay2 = fmaf(n6, bfHi(u6), ay2);
    ax3 = fmaf(n7, bfLo(u7), ax3); ay3 = fmaf(n7, bfHi(u7), ay3);
  }
  for (; i < n; ++i) {
    int2 e = edges[start + i];
    float nrm = __int_as_float(e.y);
    uint32_t u = m32[(size_t)e.x * 64 + lane];
    ax0 = fmaf(nrm, bfLo(u), ax0);
    ay0 = fmaf(nrm, bfHi(u), ay0);
  }
  float ax = (ax0 + ax1) + (ax2 + ax3) + bias[2 * lane];
  float ay = (ay0 + ay1) + (ay2 + ay3) + bias[2 * lane + 1];
  ax = fmaxf(ax, 0.f);
  ay = fmaxf(ay, 0.f);
  ushort2 h2;
  h2.x = f2bf(ax);
  h2.y = f2bf(ay);
  ((ushort2*)Hout)[(size_t)v * 64 + lane] = h2;
}

// ---------------- pool v4: P = coefB x h2 via MFMA -----------------------
// wave = (ck, nt, mt): K-chunk ck (512 nodes), n-tile nt (16 feats),
// m-tile mt (16 graphs). coefB bf16 [64][N_PAD] (pad cols = 0 -> inert).
// 4 waves/block share (ck, nt) -> identical B loads, L1-hot.
__global__ __launch_bounds__(256) void pool_mfma(const ushort* __restrict__ h2,
                                                 const ushort* __restrict__ coefB,
                                                 float* __restrict__ P) {
  int wave = (blockIdx.x * 256 + threadIdx.x) >> 6;
  int lane = threadIdx.x & 63;
  int mt = wave & 3;
  int nt = (wave >> 2) & 7;
  int ck = wave >> 5;
  if (ck >= NCHUNKS) return;
  int c0 = ck * PCHUNK;
  int m0 = mt * 16, n0 = nt * 16;
  int r = lane & 15, quad = lane >> 4;
  floatx4 acc = {0.f, 0.f, 0.f, 0.f};
  const ushort* arow = coefB + (size_t)(m0 + r) * N_PAD + c0;
#pragma unroll 4
  for (int kb = 0; kb < 16; ++kb) {
    int k0 = kb * 32 + quad * 8;
    short8 a = *(const short8*)(arow + k0);
    short8 b;
#pragma unroll
    for (int j = 0; j < 8; ++j)
      b[j] = (short)h2[(size_t)(c0 + k0 + j) * FEAT + n0 + r];
    acc = __builtin_amdgcn_mfma_f32_16x16x32_bf16(a, b, acc, 0, 0, 0);
  }
#pragma unroll
  for (int reg = 0; reg < 4; ++reg) {
    int row = quad * 4 + reg;                    // graph within m-tile
    atomicAdd(&P[(size_t)(m0 + row) * FEAT + n0 + r], acc[reg]);
  }
}

// ---------------- Pn = P / cnt  (before the W3 GEMM) ---------------------
__global__ __launch_bounds__(256) void finalize_pre(const float* __restrict__ P,
                                                    const float* __restrict__ cnt_g,
                                                    float* __restrict__ Pn) {
  int i = blockIdx.x * 256 + threadIdx.x;
  if (i < NGRAPH * FEAT) {
    float c = fmaxf(cnt_g[i >> 7], 1.0f);
    Pn[i] = P[i] / c;
  }
}

// ---------------- FC: split-K atomic GEMM, bias folded into kc==0 --------
__global__ __launch_bounds__(256) void fc_accum(const float* __restrict__ in,
                                                const float* __restrict__ w,
                                                const float* __restrict__ b,
                                                float* __restrict__ out,
                                                int K, int C, int relu_in,
                                                int cstrips, int kchunks) {
  int wave = (blockIdx.x * 256 + threadIdx.x) >> 6;
  int lane = threadIdx.x & 63;
  int perrow = cstrips * kchunks;
  int r = wave / perrow;
  if (r >= NGRAPH) return;
  int rem = wave - r * perrow;
  int cs = rem / kchunks;
  int kc = rem - cs * kchunks;
  int c = cs * 64 + lane;
  if (c >= C) return;
  const float* inr = in + (size_t)r * K + kc * 64;
  const float* wp = w + (size_t)(kc * 64) * C + c;
  float a0 = (kc == 0) ? b[c] : 0.f;
  float a1 = 0.f, a2 = 0.f, a3 = 0.f;
#pragma unroll 4
  for (int k = 0; k < 64; k += 4) {
    float i0 = inr[k], i1 = inr[k + 1], i2 = inr[k + 2], i3 = inr[k + 3];
    if (relu_in) {
      i0 = fmaxf(i0, 0.f); i1 = fmaxf(i1, 0.f);
      i2 = fmaxf(i2, 0.f); i3 = fmaxf(i3, 0.f);
    }
    a0 = fmaf(i0, wp[(size_t)k * C], a0);
    a1 = fmaf(i1, wp[(size_t)(k + 1) * C], a1);
    a2 = fmaf(i2, wp[(size_t)(k + 2) * C], a2);
    a3 = fmaf(i3, wp[(size_t)(k + 3) * C], a3);
  }
  atomicAdd(&out[(size_t)r * C + c], (a0 + a1) + (a2 + a3));
}

static inline void fc_run(const float* in, const float* w, const float* b,
                          float* out, int K, int C, int relu_in,
                          hipStream_t stream) {
  int cstrips = (C + 63) / 64;
  int kchunks = K / 64;
  int waves = NGRAPH * cstrips * kchunks;
  fc_accum<<<(waves * 64 + 255) / 256, 256, 0, stream>>>(in, w, b, out, K, C,
                                                         relu_in, cstrips, kchunks);
}

// =========================================================================
extern "C" void kernel_launch(void* const* d_in, const int* in_sizes, int n_in,
                              void* d_out, int out_size, void* d_ws, size_t ws_size,
                              hipStream_t stream) {
  const float* x         = (const float*)d_in[0];
  const int*   ei        = (const int*)d_in[1];     // [2][E]: row0 src, row1 dst
  const int*   batch     = (const int*)d_in[2];
  const float* conv_w[3] = {(const float*)d_in[3], (const float*)d_in[5], (const float*)d_in[7]};
  const float* conv_b[3] = {(const float*)d_in[4], (const float*)d_in[6], (const float*)d_in[8]};
  const float* fc_w[5]   = {(const float*)d_in[9],  (const float*)d_in[11],
                            (const float*)d_in[13], (const float*)d_in[15],
                            (const float*)d_in[17]};
  const float* fc_b[5]   = {(const float*)d_in[10], (const float*)d_in[12],
                            (const float*)d_in[14], (const float*)d_in[16],
                            (const float*)d_in[18]};
  const int* e_src = ei;
  const int* e_dst = ei + N_EDGES;
  float* out_f = (float*)d_out;                  // [64][128] fp32  (output 0)
  float* out_y = (float*)d_out + NGRAPH * FEAT;  // [64][10]  fp32  (output 1)

  char* p = (char*)d_ws;
  auto carve = [&](size_t bytes) {
    char* r = p;
    p += (bytes + 255) & ~(size_t)255;
    return r;
  };
  int*    cnt_i   = (int*)carve(N_NODES * 4);
  float*  dinv    = (float*)carve(N_NODES * 4);
  int*    csr_ptr = (int*)carve(N_NODES * 4);
  int*    cursor  = (int*)carve(N_NODES * 4);
  int*    bsums   = (int*)carve(256 * 4);
  int2*   edges   = (int2*)carve((size_t)N_EDGES * 8);
  int*    ebg     = (int*)carve((size_t)N_EDGES * 4);             // graph per CSR pos
  ushort* xb      = (ushort*)carve((size_t)N_NODES * FEAT * 2);   // bf16 x
  ushort* wb      = (ushort*)carve((size_t)2 * FEAT * FEAT * 2);  // bf16 conv1/2 W
  ushort* msl     = (ushort*)carve((size_t)N_NODES * FEAT * 2);   // bf16 messages
  ushort* hbuf    = (ushort*)carve((size_t)N_PAD * FEAT * 2);     // bf16 h (padded rows)
  float*  coefT   = (float*)carve((size_t)NGRAPH * N_PAD * 4);    // fp32, padded
  ushort* coefB   = (ushort*)carve((size_t)NGRAPH * N_PAD * 2);   // bf16, padded
  float*  f_sum   = (float*)carve(NGRAPH * FEAT * 4);             // P
  float*  cnt_g   = (float*)carve(NGRAPH * 4);                    // adjacent to f_sum
  float*  pnorm   = (float*)carve(NGRAPH * FEAT * 4);             // P/cnt
  float*  act1    = (float*)carve(NGRAPH * 1024 * 4);             // contiguous act block
  float*  act2    = (float*)carve(NGRAPH * 512 * 4);
  float*  act3    = (float*)carve(NGRAPH * 256 * 4);
  float*  act4    = (float*)carve(NGRAPH * 128 * 4);

  const int BLK_E = (N_EDGES + 255) / 256;
  const int BLK_N = (N_NODES + 255) / 256;

  // zero-init (ws + out are poisoned 0xAA each timed call)
  hipMemsetAsync(cnt_i, 0, N_NODES * 4, stream);
  hipMemsetAsync(coefT, 0, (size_t)NGRAPH * N_PAD * 4, stream);   // pad cols stay 0
  hipMemsetAsync(f_sum, 0, NGRAPH * FEAT * 4 + 256, stream);      // f_sum + cnt_g
  hipMemsetAsync(act1, 0, (size_t)NGRAPH * (1024 + 512 + 256 + 128) * 4 + 3 * 256, stream);
  hipMemsetAsync(d_out, 0, (size_t)out_size * 4, stream);         // fc targets

  // ---- fp32 -> bf16 prep (x, conv1/2 weights; conv3 stays fp32) ----
  cvt_bf16<<<(N_NODES * FEAT / 4 + 255) / 256, 256, 0, stream>>>(x, xb, N_NODES * FEAT / 4);
  cvt_bf16<<<(FEAT * FEAT / 4 + 255) / 256, 256, 0, stream>>>(conv_w[0], wb,               FEAT * FEAT / 4);
  cvt_bf16<<<(FEAT * FEAT / 4 + 255) / 256, 256, 0, stream>>>(conv_w[1], wb + FEAT * FEAT, FEAT * FEAT / 4);

  // ---- build CSR + norms + coefT ----
  count_deg<<<BLK_E, 256, 0, stream>>>(e_dst, cnt_i);
  compute_dinv<<<BLK_N, 256, 0, stream>>>(cnt_i, batch, dinv, coefT, cnt_g);
  scan1<<<BLK_N, 256, 0, stream>>>(cnt_i, csr_ptr, bsums);
  scan2<<<1, 256, 0, stream>>>(bsums, BLK_N);
  scan3<<<BLK_N, 256, 0, stream>>>(csr_ptr, cursor, bsums);
  fill_csr<<<BLK_E, 256, 0, stream>>>(e_src, e_dst, dinv, batch, cursor, edges, ebg);
  coef_build<<<BLK_E, 256, 0, stream>>>(edges, ebg, coefT);
  // coefT -> bf16 (padded layout is uniform, plain vector convert)
  cvt_bf16<<<(NGRAPH * N_PAD / 4 + 255) / 256, 256, 0, stream>>>(coefT, coefB,
                                                                 NGRAPH * N_PAD / 4);

  const int GEMM_BLKS = (N_NODES / 16) * 8 / 4;
  const int AGG_BLKS  = (N_NODES + 3) / 4;
  const int POOL_BLKS = (NCHUNKS * 8 * 4) / 4;   // 784

  // ---- conv1 ----
  gemm128<<<GEMM_BLKS, 256, 0, stream>>>(xb, wb, msl, N_NODES / 16);
  agg_kernel<<<AGG_BLKS, 256, 0, stream>>>(msl, dinv, csr_ptr, cnt_i, edges,
                                           conv_b[0], hbuf);
  // ---- conv2 ----
  gemm128<<<GEMM_BLKS, 256, 0, stream>>>(hbuf, wb + FEAT * FEAT, msl, N_NODES / 16);
  agg_kernel<<<AGG_BLKS, 256, 0, stream>>>(msl, dinv, csr_ptr, cnt_i, edges,
                                           conv_b[1], hbuf);
  // ---- conv3 (algebraic): MFMA pool of h2, then tiny GEMM with W3 ----
  pool_mfma<<<POOL_BLKS, 256, 0, stream>>>(hbuf, coefB, f_sum);
  finalize_pre<<<(NGRAPH * FEAT + 255) / 256, 256, 0, stream>>>(f_sum, cnt_g, pnorm);
  fc_run(pnorm, conv_w[2], conv_b[2], out_f, 128, 128, 0, stream);  // f = Pn*W3 + b3

  // ---- FC head: split-K atomic GEMMs, relu fused into next layer's read ----
  fc_run(out_f, fc_w[0], fc_b[0], act1, 128, 1024, 0, stream);
  fc_run(act1,  fc_w[1], fc_b[1], act2, 1024, 512, 1, stream);
  fc_run(act2,  fc_w[2], fc_b[2], act3, 512, 256, 1, stream);
  fc_run(act3,  fc_w[3], fc_b[3], act4, 256, 128, 1, stream);
  fc_run(act4,  fc_w[4], fc_b[4], out_y, 128, 10, 1, stream);
}

// Round 13
// 429.758 us; speedup vs baseline: 2.1382x; 1.0403x over previous
//
#include <hip/hip_runtime.h>
#include <stdint.h>

#define N_NODES 50000
#define N_EDGES 800000
#define N_PAD   50176    // 98 * 512, K-padding for MFMA pool
#define FEAT    128
#define NGRAPH  64
#define PCHUNK  512
#define NCHUNKS (N_PAD / PCHUNK)   // 98

typedef __attribute__((ext_vector_type(8))) short short8;
typedef __attribute__((ext_vector_type(4))) float floatx4;

static __device__ __forceinline__ ushort f2bf(float f) {
  uint32_t x = __float_as_uint(f);
  x += 0x7FFF + ((x >> 16) & 1);   // RNE
  return (ushort)(x >> 16);
}
static __device__ __forceinline__ float bfLo(uint32_t u) {
  return __uint_as_float(u << 16);
}
static __device__ __forceinline__ float bfHi(uint32_t u) {
  return __uint_as_float(u & 0xFFFF0000u);
}

// ---------------- fp32 -> bf16 row-major ---------------------------------
__global__ __launch_bounds__(256) void cvt_bf16(const float* __restrict__ in,
                                                ushort* __restrict__ out, int n4) {
  int i = blockIdx.x * 256 + threadIdx.x;
  if (i >= n4) return;
  float4 v = ((const float4*)in)[i];
  ushort4 u;
  u.x = f2bf(v.x); u.y = f2bf(v.y); u.z = f2bf(v.z); u.w = f2bf(v.w);
  ((ushort4*)out)[i] = u;
}

// ---------------- degree count -------------------------------------------
__global__ __launch_bounds__(256) void count_deg(const int* __restrict__ dst,
                                                 int* __restrict__ cnt) {
  int e = blockIdx.x * 256 + threadIdx.x;
  if (e < N_EDGES) atomicAdd(&cnt[dst[e]], 1);
}

// dinv + coef self-term + per-graph node counts (LDS binned)
__global__ __launch_bounds__(256) void compute_dinv(const int* __restrict__ cnt,
                                                    const int* __restrict__ batch,
                                                    float* __restrict__ dinv,
                                                    float* __restrict__ coefT,
                                                    float* __restrict__ cnt_g) {
  __shared__ int bins[NGRAPH];
  if (threadIdx.x < NGRAPH) bins[threadIdx.x] = 0;
  __syncthreads();
  int i = blockIdx.x * 256 + threadIdx.x;
  if (i < N_NODES) {
    float di = rsqrtf((float)cnt[i] + 1.0f);
    dinv[i] = di;
    int g = batch[i];
    coefT[(size_t)g * N_PAD + i] = di * di;   // coalesced (batch sorted)
    atomicAdd(&bins[g], 1);
  }
  __syncthreads();
  if (threadIdx.x < NGRAPH && bins[threadIdx.x] > 0)
    atomicAdd(&cnt_g[threadIdx.x], (float)bins[threadIdx.x]);
}

// ---------------- exclusive scan (3 kernels) -----------------------------
__global__ __launch_bounds__(256) void scan1(const int* __restrict__ cnt,
                                             int* __restrict__ ptr,
                                             int* __restrict__ bsums) {
  __shared__ int tmp[256];
  int i = blockIdx.x * 256 + threadIdx.x;
  int v = (i < N_NODES) ? cnt[i] : 0;
  tmp[threadIdx.x] = v;
  __syncthreads();
  for (int off = 1; off < 256; off <<= 1) {
    int t = (threadIdx.x >= off) ? tmp[threadIdx.x - off] : 0;
    __syncthreads();
    tmp[threadIdx.x] += t;
    __syncthreads();
  }
  if (i < N_NODES) ptr[i] = tmp[threadIdx.x] - v;           // exclusive
  if (threadIdx.x == 255) bsums[blockIdx.x] = tmp[255];
}

__global__ __launch_bounds__(256) void scan2(int* __restrict__ bsums, int nb) {
  __shared__ int tmp[256];
  int v = (threadIdx.x < nb) ? bsums[threadIdx.x] : 0;
  tmp[threadIdx.x] = v;
  __syncthreads();
  for (int off = 1; off < 256; off <<= 1) {
    int t = (threadIdx.x >= off) ? tmp[threadIdx.x - off] : 0;
    __syncthreads();
    tmp[threadIdx.x] += t;
    __syncthreads();
  }
  if (threadIdx.x < nb) bsums[threadIdx.x] = tmp[threadIdx.x] - v;  // exclusive
}

__global__ __launch_bounds__(256) void scan3(int* __restrict__ ptr,
                                             int* __restrict__ cursor,
                                             const int* __restrict__ bsums) {
  int i = blockIdx.x * 256 + threadIdx.x;
  if (i < N_NODES) {
    int p = ptr[i] + bsums[blockIdx.x];
    ptr[i] = p;
    cursor[i] = p;
  }
}

// ---------------- CSR fill + fused coef edge terms (r10-proven) ----------
__global__ __launch_bounds__(256) void fill_csr(const int* __restrict__ src,
                                                const int* __restrict__ dst,
                                                const float* __restrict__ dinv,
                                                const int* __restrict__ batch,
                                                int* __restrict__ cursor,
                                                int2* __restrict__ edges,
                                                float* __restrict__ coefT) {
  int e = blockIdx.x * 256 + threadIdx.x;
  if (e >= N_EDGES) return;
  int s = src[e], d = dst[e];
  int pos = atomicAdd(&cursor[d], 1);
  float nrm = dinv[s] * dinv[d];
  edges[pos] = make_int2(s, __float_as_int(nrm));
  atomicAdd(&coefT[(size_t)batch[d] * N_PAD + s], nrm);
}

// ---------------- GEMM [M,128] x [128,128] via MFMA bf16, bf16 out -------
__global__ __launch_bounds__(256) void gemm128(const ushort* __restrict__ X,
                                               const ushort* __restrict__ W,
                                               ushort* __restrict__ XW,
                                               int nTilesM) {
  int wave = (blockIdx.x * 256 + threadIdx.x) >> 6;
  int lane = threadIdx.x & 63;
  int mt = wave >> 3;  // 8 n-tiles per m-tile
  int nt = wave & 7;
  if (mt >= nTilesM) return;
  int m0 = mt * 16, n0 = nt * 16;
  int r = lane & 15, quad = lane >> 4;
  floatx4 acc = {0.f, 0.f, 0.f, 0.f};
  const ushort* xrow = X + (size_t)(m0 + r) * FEAT;
#pragma unroll
  for (int kb = 0; kb < 4; ++kb) {
    int k0 = kb * 32 + quad * 8;
    short8 a = *(const short8*)(xrow + k0);
    short8 b;
#pragma unroll
    for (int j = 0; j < 8; ++j) b[j] = (short)W[(size_t)(k0 + j) * FEAT + n0 + r];
    acc = __builtin_amdgcn_mfma_f32_16x16x32_bf16(a, b, acc, 0, 0, 0);
  }
#pragma unroll
  for (int reg = 0; reg < 4; ++reg) {
    int row = quad * 4 + reg;
    XW[(size_t)(m0 + row) * FEAT + n0 + r] = f2bf(acc[reg]);
  }
}

// ---------------- aggregation (r6 proven): wave/node, 8-edge ILP ---------
__global__ __launch_bounds__(256) void agg_kernel(const ushort* __restrict__ msg,
                                                  const float* __restrict__ dinv,
                                                  const int* __restrict__ ptr,
                                                  const int* __restrict__ cnt,
                                                  const int2* __restrict__ edges,
                                                  const float* __restrict__ bias,
                                                  ushort* __restrict__ Hout) {
  int wave = (blockIdx.x * 256 + threadIdx.x) >> 6;
  int lane = threadIdx.x & 63;
  if (wave >= N_NODES) return;
  int v = wave;
  float di = dinv[v];
  const uint32_t* m32 = (const uint32_t*)msg;   // 64 dwords per node row
  uint32_t su = m32[(size_t)v * 64 + lane];
  float sn = di * di;
  float ax0 = bfLo(su) * sn, ay0 = bfHi(su) * sn;
  float ax1 = 0.f, ay1 = 0.f, ax2 = 0.f, ay2 = 0.f, ax3 = 0.f, ay3 = 0.f;
  int start = ptr[v];
  int n = cnt[v];
  int i = 0;
  if ((start & 1) && n > 0) {
    int2 e = edges[start];
    uint32_t u = m32[(size_t)e.x * 64 + lane];
    float nrm = __int_as_float(e.y);
    ax0 = fmaf(nrm, bfLo(u), ax0);
    ay0 = fmaf(nrm, bfHi(u), ay0);
    i = 1;
  }
  for (; i + 8 <= n; i += 8) {
    const int4* ep = (const int4*)(edges + start + i);   // 16B-aligned
    int4 q0 = ep[0], q1 = ep[1], q2 = ep[2], q3 = ep[3];
    uint32_t u0 = m32[(size_t)q0.x * 64 + lane];
    uint32_t u1 = m32[(size_t)q0.z * 64 + lane];
    uint32_t u2 = m32[(size_t)q1.x * 64 + lane];
    uint32_t u3 = m32[(size_t)q1.z * 64 + lane];
    uint32_t u4 = m32[(size_t)q2.x * 64 + lane];
    uint32_t u5 = m32[(size_t)q2.z * 64 + lane];
    uint32_t u6 = m32[(size_t)q3.x * 64 + lane];
    uint32_t u7 = m32[(size_t)q3.z * 64 + lane];
    float n0 = __int_as_float(q0.y), n1 = __int_as_float(q0.w);
    float n2 = __int_as_float(q1.y), n3 = __int_as_float(q1.w);
    float n4 = __int_as_float(q2.y), n5 = __int_as_float(q2.w);
    float n6 = __int_as_float(q3.y), n7 = __int_as_float(q3.w);
    ax0 = fmaf(n0, bfLo(u0), ax0); ay0 = fmaf(n0, bfHi(u0), ay0);
    ax1 = fmaf(n1, bfLo(u1), ax1); ay1 = fmaf(n1, bfHi(u1), ay1);
    ax2 = fmaf(n2, bfLo(u2), ax2); ay2 = fmaf(n2, bfHi(u2), ay2);
    ax3 = fmaf(n3, bfLo(u3), ax3); ay3 = fmaf(n3, bfHi(u3), ay3);
    ax0 = fmaf(n4, bfLo(u4), ax0); ay0 = fmaf(n4, bfHi(u4), ay0);
    ax1 = fmaf(n5, bfLo(u5), ax1); ay1 = fmaf(n5, bfHi(u5), ay1);
    ax2 = fmaf(n6, bfLo(u6), ax2); ay2 = fmaf(n6, bfHi(u6), ay2);
    ax3 = fmaf(n7, bfLo(u7), ax3); ay3 = fmaf(n7, bfHi(u7), ay3);
  }
  for (; i < n; ++i) {
    int2 e = edges[start + i];
    float nrm = __int_as_float(e.y);
    uint32_t u = m32[(size_t)e.x * 64 + lane];
    ax0 = fmaf(nrm, bfLo(u), ax0);
    ay0 = fmaf(nrm, bfHi(u), ay0);
  }
  float ax = (ax0 + ax1) + (ax2 + ax3) + bias[2 * lane];
  float ay = (ay0 + ay1) + (ay2 + ay3) + bias[2 * lane + 1];
  ax = fmaxf(ax, 0.f);
  ay = fmaxf(ay, 0.f);
  ushort2 h2;
  h2.x = f2bf(ax);
  h2.y = f2bf(ay);
  ((ushort2*)Hout)[(size_t)v * 64 + lane] = h2;
}

// ---------------- pool v4: P = coefB x h2 via MFMA -----------------------
__global__ __launch_bounds__(256) void pool_mfma(const ushort* __restrict__ h2,
                                                 const ushort* __restrict__ coefB,
                                                 float* __restrict__ P) {
  int wave = (blockIdx.x * 256 + threadIdx.x) >> 6;
  int lane = threadIdx.x & 63;
  int mt = wave & 3;
  int nt = (wave >> 2) & 7;
  int ck = wave >> 5;
  if (ck >= NCHUNKS) return;
  int c0 = ck * PCHUNK;
  int m0 = mt * 16, n0 = nt * 16;
  int r = lane & 15, quad = lane >> 4;
  floatx4 acc = {0.f, 0.f, 0.f, 0.f};
  const ushort* arow = coefB + (size_t)(m0 + r) * N_PAD + c0;
#pragma unroll 4
  for (int kb = 0; kb < 16; ++kb) {
    int k0 = kb * 32 + quad * 8;
    short8 a = *(const short8*)(arow + k0);
    short8 b;
#pragma unroll
    for (int j = 0; j < 8; ++j)
      b[j] = (short)h2[(size_t)(c0 + k0 + j) * FEAT + n0 + r];
    acc = __builtin_amdgcn_mfma_f32_16x16x32_bf16(a, b, acc, 0, 0, 0);
  }
#pragma unroll
  for (int reg = 0; reg < 4; ++reg) {
    int row = quad * 4 + reg;                    // graph within m-tile
    atomicAdd(&P[(size_t)(m0 + row) * FEAT + n0 + r], acc[reg]);
  }
}

// ---------------- fused head: Pn = P/cnt; f = Pn*W3+b3; fc1..fc5 ---------
// One block per graph (64 blocks x 1024 threads). Activations in LDS
// ping-pong; weights streamed from L2 (shared by all blocks). Each layer
// k-splits across thread groups (Cp-wide, pow2) with LDS-atomic combine.
__device__ __forceinline__ void head_layer(const float* __restrict__ IN,
                                           float* __restrict__ OUT,
                                           const float* __restrict__ w,
                                           const float* __restrict__ b,
                                           int K, int C, int Cp, int relu,
                                           float* __restrict__ gout, int t) {
  int parts = 1024 / Cp;
  int part = t / Cp;
  int c = t - part * Cp;
  int kchunk = K / parts;
  // init OUT with bias
  if (t < C) OUT[t] = b[t];
  __syncthreads();
  if (c < C) {
    int k0 = part * kchunk;
    float a0 = 0.f, a1 = 0.f, a2 = 0.f, a3 = 0.f;
    const float* wp = w + (size_t)k0 * C + c;
    if ((kchunk & 3) == 0) {
#pragma unroll 4
      for (int k = 0; k < kchunk; k += 4) {
        a0 = fmaf(IN[k0 + k],     wp[(size_t)k * C],       a0);
        a1 = fmaf(IN[k0 + k + 1], wp[(size_t)(k + 1) * C], a1);
        a2 = fmaf(IN[k0 + k + 2], wp[(size_t)(k + 2) * C], a2);
        a3 = fmaf(IN[k0 + k + 3], wp[(size_t)(k + 3) * C], a3);
      }
    } else {
      for (int k = 0; k < kchunk; ++k)
        a0 = fmaf(IN[k0 + k], wp[(size_t)k * C], a0);
    }
    atomicAdd(&OUT[c], (a0 + a1) + (a2 + a3));
  }
  __syncthreads();
  // finalize: relu / global write
  if (t < C) {
    float v = OUT[t];
    if (relu) { v = fmaxf(v, 0.f); OUT[t] = v; }
    if (gout) gout[t] = v;
  }
  __syncthreads();
}

__global__ __launch_bounds__(1024) void fc_head(const float* __restrict__ P,
                                                const float* __restrict__ cnt_g,
                                                const float* __restrict__ w3,
                                                const float* __restrict__ b3,
                                                const float* __restrict__ w1,
                                                const float* __restrict__ b1,
                                                const float* __restrict__ w2,
                                                const float* __restrict__ b2,
                                                const float* __restrict__ wf3,
                                                const float* __restrict__ bf3,
                                                const float* __restrict__ w4,
                                                const float* __restrict__ b4,
                                                const float* __restrict__ w5,
                                                const float* __restrict__ b5,
                                                float* __restrict__ out_f,
                                                float* __restrict__ out_y) {
  __shared__ float A[1024];
  __shared__ float B[1024];
  int r = blockIdx.x, t = threadIdx.x;
  if (t < FEAT) A[t] = P[r * FEAT + t] / fmaxf(cnt_g[r], 1.0f);   // Pn
  __syncthreads();
  // conv3 weight layer: f = Pn*W3 + b3 (no relu), write out_f + keep in B
  head_layer(A, B, w3, b3, 128, 128, 128, 0, out_f + (size_t)r * FEAT, t);
  // fc1..fc4 with relu at write; fc5 plain -> out_y
  head_layer(B, A, w1, b1, 128, 1024, 1024, 1, nullptr, t);
  head_layer(A, B, w2, b2, 1024, 512, 512, 1, nullptr, t);
  head_layer(B, A, wf3, bf3, 512, 256, 256, 1, nullptr, t);
  head_layer(A, B, w4, b4, 256, 128, 128, 1, nullptr, t);
  head_layer(B, A, w5, b5, 128, 10, 16, 0, out_y + (size_t)r * 10, t);
}

// =========================================================================
extern "C" void kernel_launch(void* const* d_in, const int* in_sizes, int n_in,
                              void* d_out, int out_size, void* d_ws, size_t ws_size,
                              hipStream_t stream) {
  const float* x         = (const float*)d_in[0];
  const int*   ei        = (const int*)d_in[1];     // [2][E]: row0 src, row1 dst
  const int*   batch     = (const int*)d_in[2];
  const float* conv_w[3] = {(const float*)d_in[3], (const float*)d_in[5], (const float*)d_in[7]};
  const float* conv_b[3] = {(const float*)d_in[4], (const float*)d_in[6], (const float*)d_in[8]};
  const float* fc_w[5]   = {(const float*)d_in[9],  (const float*)d_in[11],
                            (const float*)d_in[13], (const float*)d_in[15],
                            (const float*)d_in[17]};
  const float* fc_b[5]   = {(const float*)d_in[10], (const float*)d_in[12],
                            (const float*)d_in[14], (const float*)d_in[16],
                            (const float*)d_in[18]};
  const int* e_src = ei;
  const int* e_dst = ei + N_EDGES;
  float* out_f = (float*)d_out;                  // [64][128] fp32  (output 0)
  float* out_y = (float*)d_out + NGRAPH * FEAT;  // [64][10]  fp32  (output 1)

  char* p = (char*)d_ws;
  auto carve = [&](size_t bytes) {
    char* r = p;
    p += (bytes + 255) & ~(size_t)255;
    return r;
  };
  int*    cnt_i   = (int*)carve(N_NODES * 4);
  float*  dinv    = (float*)carve(N_NODES * 4);
  int*    csr_ptr = (int*)carve(N_NODES * 4);
  int*    cursor  = (int*)carve(N_NODES * 4);
  int*    bsums   = (int*)carve(256 * 4);
  int2*   edges   = (int2*)carve((size_t)N_EDGES * 8);
  ushort* xb      = (ushort*)carve((size_t)N_NODES * FEAT * 2);   // bf16 x
  ushort* wb      = (ushort*)carve((size_t)2 * FEAT * FEAT * 2);  // bf16 conv1/2 W
  ushort* msl     = (ushort*)carve((size_t)N_NODES * FEAT * 2);   // bf16 messages
  ushort* hbuf    = (ushort*)carve((size_t)N_PAD * FEAT * 2);     // bf16 h (padded)
  float*  coefT   = (float*)carve((size_t)NGRAPH * N_PAD * 4);    // fp32, padded
  ushort* coefB   = (ushort*)carve((size_t)NGRAPH * N_PAD * 2);   // bf16, padded
  float*  f_sum   = (float*)carve(NGRAPH * FEAT * 4);             // P
  float*  cnt_g   = (float*)carve(NGRAPH * 4);                    // adjacent to f_sum

  const int BLK_E = (N_EDGES + 255) / 256;
  const int BLK_N = (N_NODES + 255) / 256;

  // zero-init (ws + out are poisoned 0xAA each timed call)
  hipMemsetAsync(cnt_i, 0, N_NODES * 4, stream);
  hipMemsetAsync(coefT, 0, (size_t)NGRAPH * N_PAD * 4, stream);   // pad cols stay 0
  hipMemsetAsync(f_sum, 0, NGRAPH * FEAT * 4 + 256, stream);      // f_sum + cnt_g

  // ---- fp32 -> bf16 prep (x, conv1/2 weights; conv3 stays fp32) ----
  cvt_bf16<<<(N_NODES * FEAT / 4 + 255) / 256, 256, 0, stream>>>(x, xb, N_NODES * FEAT / 4);
  cvt_bf16<<<(FEAT * FEAT / 4 + 255) / 256, 256, 0, stream>>>(conv_w[0], wb,               FEAT * FEAT / 4);
  cvt_bf16<<<(FEAT * FEAT / 4 + 255) / 256, 256, 0, stream>>>(conv_w[1], wb + FEAT * FEAT, FEAT * FEAT / 4);

  // ---- build CSR + norms + coefT (edge terms fused into fill) ----
  count_deg<<<BLK_E, 256, 0, stream>>>(e_dst, cnt_i);
  compute_dinv<<<BLK_N, 256, 0, stream>>>(cnt_i, batch, dinv, coefT, cnt_g);
  scan1<<<BLK_N, 256, 0, stream>>>(cnt_i, csr_ptr, bsums);
  scan2<<<1, 256, 0, stream>>>(bsums, BLK_N);
  scan3<<<BLK_N, 256, 0, stream>>>(csr_ptr, cursor, bsums);
  fill_csr<<<BLK_E, 256, 0, stream>>>(e_src, e_dst, dinv, batch, cursor, edges, coefT);
  // coefT -> bf16 (padded layout is uniform, plain vector convert)
  cvt_bf16<<<(NGRAPH * N_PAD / 4 + 255) / 256, 256, 0, stream>>>(coefT, coefB,
                                                                 NGRAPH * N_PAD / 4);

  const int GEMM_BLKS = (N_NODES / 16) * 8 / 4;
  const int AGG_BLKS  = (N_NODES + 3) / 4;
  const int POOL_BLKS = (NCHUNKS * 8 * 4) / 4;   // 784

  // ---- conv1 ----
  gemm128<<<GEMM_BLKS, 256, 0, stream>>>(xb, wb, msl, N_NODES / 16);
  agg_kernel<<<AGG_BLKS, 256, 0, stream>>>(msl, dinv, csr_ptr, cnt_i, edges,
                                           conv_b[0], hbuf);
  // ---- conv2 ----
  gemm128<<<GEMM_BLKS, 256, 0, stream>>>(hbuf, wb + FEAT * FEAT, msl, N_NODES / 16);
  agg_kernel<<<AGG_BLKS, 256, 0, stream>>>(msl, dinv, csr_ptr, cnt_i, edges,
                                           conv_b[1], hbuf);
  // ---- conv3 (algebraic): MFMA pool of h2 ----
  pool_mfma<<<POOL_BLKS, 256, 0, stream>>>(hbuf, coefB, f_sum);

  // ---- fused head: Pn -> W3 -> fc1..fc5 (one launch) ----
  fc_head<<<NGRAPH, 1024, 0, stream>>>(f_sum, cnt_g, conv_w[2], conv_b[2],
                                       fc_w[0], fc_b[0], fc_w[1], fc_b[1],
                                       fc_w[2], fc_b[2], fc_w[3], fc_b[3],
                                       fc_w[4], fc_b[4], out_f, out_y);
}